// Round 2
// baseline (575.069 us; speedup 1.0000x reference)
//
#include <hip/hip_runtime.h>

typedef unsigned short ushort_t;
typedef unsigned int uint32;
typedef __attribute__((ext_vector_type(8))) short short8;
typedef __attribute__((ext_vector_type(4))) float f32x4;
typedef __attribute__((ext_vector_type(4))) unsigned int u32x4;

#define BATCH 8
#define NPTS 12544
#define CC 192
#define KCL 784
#define N2 3136
#define TOTPTS 25088        // BATCH*N2
#define OUT_FEAT_OFF 50176
#define OUT_MASK_OFF 9683968

__device__ __forceinline__ ushort_t f2bf(float f) {
    union { float f; uint32 u; } v; v.f = f;
    uint32 u = v.u;
    uint32 r = (u + 0x7FFFu + ((u >> 16) & 1u)) >> 16;
    return (ushort_t)r;
}
__device__ __forceinline__ float bf2f(ushort_t h) {
    union { uint32 u; float f; } v; v.u = ((uint32)h) << 16;
    return v.f;
}
__device__ __forceinline__ float gelu_exact(float x) {
    return 0.5f * x * (1.f + erff(x * 0.70710678118654752f));
}

// JAX threefry2x32 with key = (0, 42)  [jax.random.key(42)]
__device__ __forceinline__ void threefry(uint32 x0, uint32 x1, uint32& y0, uint32& y1) {
    const uint32 k0 = 0u, k1 = 42u;
    const uint32 k2 = 0u ^ 42u ^ 0x1BD11BDAu;
#define ROT(v,r) (((v) << (r)) | ((v) >> (32 - (r))))
#define RND(r) { x0 += x1; x1 = ROT(x1, r); x1 ^= x0; }
    x0 += k0; x1 += k1;
    RND(13) RND(15) RND(26) RND(6)
    x0 += k1; x1 += k2 + 1u;
    RND(17) RND(29) RND(16) RND(24)
    x0 += k2; x1 += k0 + 2u;
    RND(13) RND(15) RND(26) RND(6)
    x0 += k0; x1 += k1 + 3u;
    RND(17) RND(29) RND(16) RND(24)
    x0 += k1; x1 += k2 + 4u;
    RND(13) RND(15) RND(26) RND(6)
    x0 += k2; x1 += k0 + 5u;
    y0 = x0; y1 = x1;
#undef RND
#undef ROT
}

// ---------------- LayerNorm of feat -> bf16 ----------------
__global__ __launch_bounds__(256) void k_ln(const float* __restrict__ x,
        const float* __restrict__ g, const float* __restrict__ b,
        ushort_t* __restrict__ y)
{
    int row = blockIdx.x * 4 + (threadIdx.x >> 6);
    int lane = threadIdx.x & 63;
    const float* xr = x + (size_t)row * CC;
    float v0 = xr[lane], v1 = xr[lane + 64], v2 = xr[lane + 128];
    float s = v0 + v1 + v2;
    for (int d = 32; d >= 1; d >>= 1) s += __shfl_xor(s, d, 64);
    float mu = s * (1.f / 192.f);
    float d0 = v0 - mu, d1 = v1 - mu, d2 = v2 - mu;
    float q = d0 * d0 + d1 * d1 + d2 * d2;
    for (int d = 32; d >= 1; d >>= 1) q += __shfl_xor(q, d, 64);
    float rstd = 1.f / sqrtf(q * (1.f / 192.f) + 1e-5f);
    ushort_t* yr = y + (size_t)row * CC;
    yr[lane]       = f2bf(d0 * rstd * g[lane]       + b[lane]);
    yr[lane + 64]  = f2bf(d1 * rstd * g[lane + 64]  + b[lane + 64]);
    yr[lane + 128] = f2bf(d2 * rstd * g[lane + 128] + b[lane + 128]);
}

// ---------------- points2img scatter + 2x downsample ----------------
__global__ void k_scatter(const float* __restrict__ pos, int* __restrict__ img)
{
    int t = blockIdx.x * 256 + threadIdx.x;   // t < BATCH*NPTS
    int b = t / NPTS, n = t - b * NPTS;
    int x = (int)pos[(size_t)t * 2];
    int y = (int)pos[(size_t)t * 2 + 1];
    img[(size_t)b * NPTS + y * 112 + x] = n;
}

__global__ void k_down(const int* __restrict__ img, int* __restrict__ idxa)
{
    int q = blockIdx.x * 256 + threadIdx.x;   // q < TOTPTS
    int b = q / N2, p2 = q - b * N2;
    int r = p2 / 56, c = p2 - r * 56;
    idxa[q] = img[(size_t)b * NPTS + (2 * r) * 112 + 2 * c];
}

// ---------------- transpose lin_W -> bf16 linT[384][6144] ----------------
__global__ __launch_bounds__(256) void k_linT(const float* __restrict__ W, ushort_t* __restrict__ T)
{
    __shared__ float tile[64][65];
    int k0 = blockIdx.x * 64, n0 = blockIdx.y * 64;
    for (int s = 0; s < 16; ++s) {
        int id = threadIdx.x + s * 256;
        int i = id >> 6, j = id & 63;
        tile[i][j] = W[(size_t)(k0 + i) * 384 + n0 + j];
    }
    __syncthreads();
    for (int s = 0; s < 16; ++s) {
        int id = threadIdx.x + s * 256;
        int jj = id >> 6, ii = id & 63;
        T[(size_t)(n0 + jj) * 6144 + k0 + ii] = f2bf(tile[ii][jj]);
    }
}

// ---------------- per-point: sampling + weights + agg build ----------------
__global__ __launch_bounds__(256) void k_point(
    const float* __restrict__ pos, const float* __restrict__ maskp,
    const int* __restrict__ massign, const int* __restrict__ memidx,
    const float* __restrict__ cmaskp, const ushort_t* __restrict__ featn,
    const int* __restrict__ idxarr,
    const float* __restrict__ w1W, const float* __restrict__ w1b,
    const float* __restrict__ lng, const float* __restrict__ lnb,
    const float* __restrict__ f1W, const float* __restrict__ f1b,
    const float* __restrict__ f2W, const float* __restrict__ f2b,
    ushort_t* __restrict__ agg, float* __restrict__ outbuf, int p0)
{
    __shared__ double sc[128];
    __shared__ double rs[128];
    __shared__ int ri[128];
    __shared__ int memv[128];
    __shared__ int mcat[4];
    __shared__ float fg[4][200];
    __shared__ float prel[4][2];
    __shared__ float wsm[4][32];
    __shared__ float fwv[4];
    __shared__ float pd[2];

    int point = p0 + blockIdx.x;
    int b = point / N2;
    int tid = threadIdx.x;
    int idx_pt = idxarr[point];

    if (tid < 128) {
        int j = tid >> 4, i = tid & 15;
        int maj = massign[((size_t)b * NPTS + idx_pt) * 8 + j];
        size_t roff = ((size_t)b * KCL + maj) * 16 + i;
        int mv = memidx[roff];
        float cv = cmaskp[roff];
        if (mv == idx_pt) cv = 0.f;
        float pr = fmaxf(cv, 1e-5f);
        // JAX partitionable random_bits (default since jax 0.4.36):
        // per-element counter (hi, lo) of 64-bit flat iota; bits = y0 ^ y1.
        uint32 gi = (uint32)point * 128u + (uint32)tid;
        uint32 y0, y1;
        threefry(0u, gi, y0, y1);
        uint32 bits = y0 ^ y1;
        union { uint32 u; float f; } cu; cu.u = (bits >> 9) | 0x3f800000u;
        float u = cu.f - 1.0f;
        double gum = -log(-log((double)u + 1e-20) + 1e-20);
        sc[tid] = log((double)pr) + gum;
        memv[tid] = mv;
    }
    if (tid == 128) {
        pd[0] = pos[((size_t)b * NPTS + idx_pt) * 2];
        pd[1] = pos[((size_t)b * NPTS + idx_pt) * 2 + 1];
    }
    if (tid == 129) outbuf[OUT_MASK_OFF + point] = maskp[(size_t)b * NPTS + idx_pt];
    __syncthreads();
    if (tid < 2) outbuf[(size_t)point * 2 + tid] = floorf(pd[tid] * 0.5f);

    // top-3 (desc, ties -> lower index)
    for (int pass = 0; pass < 3; ++pass) {
        if (tid < 128) { rs[tid] = sc[tid]; ri[tid] = tid; }
        __syncthreads();
        for (int off = 64; off >= 1; off >>= 1) {
            if (tid < off) {
                double s2 = rs[tid + off]; int i2 = ri[tid + off];
                if (s2 > rs[tid] || (s2 == rs[tid] && i2 < ri[tid])) { rs[tid] = s2; ri[tid] = i2; }
            }
            __syncthreads();
        }
        if (tid == 0) { int w = ri[0]; mcat[pass] = memv[w]; sc[w] = -1e308; }
        __syncthreads();
    }
    if (tid == 0) mcat[3] = idx_pt;
    __syncthreads();

    // gather 4 neighbor rows of feat_n (bf16 -> f32 LDS) + pos_rel
    int m = tid >> 6, lane = tid & 63;
    {
        size_t rbase = ((size_t)b * NPTS + mcat[m]) * CC;
        for (int jj = 0; jj < 3; ++jj) {
            int c = lane + jj * 64;
            fg[m][c] = bf2f(featn[rbase + c]);
        }
        if (lane == 0) {
            prel[m][0] = pos[((size_t)b * NPTS + mcat[m]) * 2]     - pd[0];
            prel[m][1] = pos[((size_t)b * NPTS + mcat[m]) * 2 + 1] - pd[1];
        }
    }
    __syncthreads();

    // pos MLP: (pos_rel @ w1) -> LN(32) -> gelu
    if (tid < 128) {
        int mm = tid >> 5, kk = tid & 31;
        float pre = prel[mm][0] * w1W[kk] + prel[mm][1] * w1W[32 + kk] + w1b[kk];
        float s = pre;
        for (int d = 16; d >= 1; d >>= 1) s += __shfl_xor(s, d, 32);
        float mu = s * (1.f / 32.f);
        float dv = pre - mu;
        float vs = dv * dv;
        for (int d = 16; d >= 1; d >>= 1) vs += __shfl_xor(vs, d, 32);
        float var = vs * (1.f / 32.f);
        float nv = dv / sqrtf(var + 1e-5f) * lng[kk] + lnb[kk];
        wsm[mm][kk] = gelu_exact(nv);
    }

    // feature gate: sigmoid(gelu(feat_rel @ f1) @ f2)
    {
        int o = lane;
        float acc = f1b[o];
        for (int c = 0; c < CC; ++c)
            acc += (fg[m][c] - fg[3][c]) * f1W[c * 64 + o];
        float h = gelu_exact(acc);
        float part = h * f2W[o];
        for (int d = 32; d >= 1; d >>= 1) part += __shfl_xor(part, d, 64);
        if (lane == 0) fwv[m] = 1.f / (1.f + expf(-(part + f2b[0])));
    }
    __syncthreads();
    if (tid < 128) { int mm = tid >> 5, kk = tid & 31; wsm[mm][kk] *= fwv[mm]; }
    __syncthreads();

    // agg[k][c] = sum_m w[m][k] * feat_g[m][c]  -> bf16
    size_t abase = (size_t)blockIdx.x * 6144;
    for (int ii = 0; ii < 24; ++ii) {
        int kc = ii * 256 + tid;
        int kq = kc / 192;
        int cq = kc - kq * 192;
        float v = wsm[0][kq] * fg[0][cq] + wsm[1][kq] * fg[1][cq]
                + wsm[2][kq] * fg[2][cq] + wsm[3][kq] * fg[3][cq];
        agg[abase + kc] = f2bf(v);
    }
}

// ---------------- GEMM: (cnt x 6144) @ (6144 x 384), bf16 MFMA ----------------
__global__ __launch_bounds__(256) void k_gemm(const ushort_t* __restrict__ A,
    const ushort_t* __restrict__ BT, const float* __restrict__ bias,
    float* __restrict__ out, int p0)
{
    __shared__ ushort_t As[128][40];
    __shared__ ushort_t Bs[128][40];
    int tid = threadIdx.x;
    int wave = tid >> 6, lane = tid & 63;
    int l15 = lane & 15, l4 = lane >> 4;
    int m0 = blockIdx.x * 128;
    int n0 = blockIdx.y * 128;
    int wr = (wave >> 1) * 64, wc = (wave & 1) * 64;
    f32x4 acc[4][4];
#pragma unroll
    for (int mi = 0; mi < 4; ++mi)
#pragma unroll
        for (int ni = 0; ni < 4; ++ni)
            acc[mi][ni] = (f32x4){0.f, 0.f, 0.f, 0.f};

    for (int k0 = 0; k0 < 6144; k0 += 32) {
#pragma unroll
        for (int it = 0; it < 2; ++it) {
            int id = tid + it * 256;
            int r = id >> 2, sg = id & 3;
            const u32x4* ga = (const u32x4*)(A + (size_t)(m0 + r) * 6144 + k0 + sg * 8);
            *(u32x4*)(&As[r][sg * 8]) = *ga;
            const u32x4* gb = (const u32x4*)(BT + (size_t)(n0 + r) * 6144 + k0 + sg * 8);
            *(u32x4*)(&Bs[r][sg * 8]) = *gb;
        }
        __syncthreads();
        short8 av[4], bv[4];
#pragma unroll
        for (int mi = 0; mi < 4; ++mi) av[mi] = *(const short8*)(&As[wr + mi * 16 + l15][l4 * 8]);
#pragma unroll
        for (int ni = 0; ni < 4; ++ni) bv[ni] = *(const short8*)(&Bs[wc + ni * 16 + l15][l4 * 8]);
#pragma unroll
        for (int mi = 0; mi < 4; ++mi)
#pragma unroll
            for (int ni = 0; ni < 4; ++ni)
                acc[mi][ni] = __builtin_amdgcn_mfma_f32_16x16x32_bf16(av[mi], bv[ni], acc[mi][ni], 0, 0, 0);
        __syncthreads();
    }

#pragma unroll
    for (int mi = 0; mi < 4; ++mi)
#pragma unroll
        for (int ni = 0; ni < 4; ++ni)
#pragma unroll
            for (int r = 0; r < 4; ++r) {
                int rr = wr + mi * 16 + l4 * 4 + r;
                int ccol = wc + ni * 16 + l15;
                out[(size_t)(p0 + m0 + rr) * 384 + n0 + ccol] = acc[mi][ni][r] + bias[n0 + ccol];
            }
}

extern "C" void kernel_launch(void* const* d_in, const int* in_sizes, int n_in,
                              void* d_out, int out_size, void* d_ws, size_t ws_size,
                              hipStream_t stream)
{
    const float* pos      = (const float*)d_in[0];
    const float* feat     = (const float*)d_in[1];
    const float* maskp    = (const float*)d_in[2];
    const int*   massign  = (const int*)d_in[4];
    const int*   memidx   = (const int*)d_in[5];
    const float* cmaskp   = (const float*)d_in[9];
    const float* norm_g   = (const float*)d_in[10];
    const float* norm_b   = (const float*)d_in[11];
    const float* w1W      = (const float*)d_in[12];
    const float* w1b      = (const float*)d_in[13];
    const float* lng      = (const float*)d_in[14];
    const float* lnb      = (const float*)d_in[15];
    const float* f1W      = (const float*)d_in[16];
    const float* f1b      = (const float*)d_in[17];
    const float* f2W      = (const float*)d_in[18];
    const float* f2b      = (const float*)d_in[19];
    const float* linW     = (const float*)d_in[20];
    const float* linb     = (const float*)d_in[21];

    char* ws = (char*)d_ws;
    ushort_t* featn = (ushort_t*)(ws);
    int* img   = (int*)(ws + 38535168);
    int* idxa  = (int*)(ws + 38936576);
    ushort_t* linT = (ushort_t*)(ws + 39036928);
    ushort_t* agg  = (ushort_t*)(ws + 43755520);

    size_t avail = ws_size > 43755520 ? ws_size - 43755520 : 0;
    long long slabM = (long long)(avail / 12288);
    slabM &= ~127LL;
    if (slabM > TOTPTS) slabM = TOTPTS;
    if (slabM < 128) slabM = 128;

    k_ln<<<TOTPTS, 256, 0, stream>>>(feat, norm_g, norm_b, featn);
    hipMemsetAsync(img, 0, 401408, stream);
    k_scatter<<<392, 256, 0, stream>>>(pos, img);
    k_down<<<98, 256, 0, stream>>>(img, idxa);
    k_linT<<<dim3(96, 6), 256, 0, stream>>>(linW, linT);

    float* outF = (float*)d_out;
    for (int p0 = 0; p0 < TOTPTS; p0 += (int)slabM) {
        int cnt = TOTPTS - p0; if (cnt > (int)slabM) cnt = (int)slabM;
        k_point<<<cnt, 256, 0, stream>>>(pos, maskp, massign, memidx, cmaskp, featn, idxa,
                w1W, w1b, lng, lnb, f1W, f1b, f2W, f2b, agg, outF, p0);
        k_gemm<<<dim3(cnt / 128, 3), 256, 0, stream>>>(agg, linT, linb, outF + OUT_FEAT_OFF, p0);
    }
}

// Round 4
// 495.062 us; speedup vs baseline: 1.1616x; 1.1616x over previous
//
#include <hip/hip_runtime.h>

typedef unsigned short ushort_t;
typedef unsigned int uint32;
typedef __attribute__((ext_vector_type(8))) short short8;
typedef __attribute__((ext_vector_type(4))) float f32x4;
typedef __attribute__((ext_vector_type(4))) unsigned int u32x4;

#define BATCH 8
#define NPTS 12544
#define CC 192
#define KCL 784
#define N2 3136
#define TOTPTS 25088        // BATCH*N2
#define OUT_FEAT_OFF 50176
#define OUT_MASK_OFF 9683968

__device__ __forceinline__ ushort_t f2bf(float f) {
    union { float f; uint32 u; } v; v.f = f;
    uint32 u = v.u;
    uint32 r = (u + 0x7FFFu + ((u >> 16) & 1u)) >> 16;
    return (ushort_t)r;
}
__device__ __forceinline__ float bf2f(ushort_t h) {
    union { uint32 u; float f; } v; v.u = ((uint32)h) << 16;
    return v.f;
}
__device__ __forceinline__ float gelu_exact(float x) {
    return 0.5f * x * (1.f + erff(x * 0.70710678118654752f));
}

__device__ __forceinline__ void gld16(const void* g, void* l) {
    __builtin_amdgcn_global_load_lds((const __attribute__((address_space(1))) void*)g,
                                     (__attribute__((address_space(3))) void*)l, 16, 0, 0);
}

// JAX threefry2x32 with key = (0, 42)
__device__ __forceinline__ void threefry(uint32 x0, uint32 x1, uint32& y0, uint32& y1) {
    const uint32 k0 = 0u, k1 = 42u;
    const uint32 k2 = 0u ^ 42u ^ 0x1BD11BDAu;
#define ROT(v,r) (((v) << (r)) | ((v) >> (32 - (r))))
#define RND(r) { x0 += x1; x1 = ROT(x1, r); x1 ^= x0; }
    x0 += k0; x1 += k1;
    RND(13) RND(15) RND(26) RND(6)
    x0 += k1; x1 += k2 + 1u;
    RND(17) RND(29) RND(16) RND(24)
    x0 += k2; x1 += k0 + 2u;
    RND(13) RND(15) RND(26) RND(6)
    x0 += k0; x1 += k1 + 3u;
    RND(17) RND(29) RND(16) RND(24)
    x0 += k1; x1 += k2 + 4u;
    RND(13) RND(15) RND(26) RND(6)
    x0 += k2; x1 += k0 + 5u;
    y0 = x0; y1 = x1;
#undef RND
#undef ROT
}

// ---------------- LayerNorm of feat -> bf16 ----------------
__global__ __launch_bounds__(256) void k_ln(const float* __restrict__ x,
        const float* __restrict__ g, const float* __restrict__ b,
        ushort_t* __restrict__ y)
{
    int row = blockIdx.x * 4 + (threadIdx.x >> 6);
    int lane = threadIdx.x & 63;
    const float* xr = x + (size_t)row * CC;
    float v0 = xr[lane], v1 = xr[lane + 64], v2 = xr[lane + 128];
    float s = v0 + v1 + v2;
    for (int d = 32; d >= 1; d >>= 1) s += __shfl_xor(s, d, 64);
    float mu = s * (1.f / 192.f);
    float d0 = v0 - mu, d1 = v1 - mu, d2 = v2 - mu;
    float q = d0 * d0 + d1 * d1 + d2 * d2;
    for (int d = 32; d >= 1; d >>= 1) q += __shfl_xor(q, d, 64);
    float rstd = 1.f / sqrtf(q * (1.f / 192.f) + 1e-5f);
    ushort_t* yr = y + (size_t)row * CC;
    yr[lane]       = f2bf(d0 * rstd * g[lane]       + b[lane]);
    yr[lane + 64]  = f2bf(d1 * rstd * g[lane + 64]  + b[lane + 64]);
    yr[lane + 128] = f2bf(d2 * rstd * g[lane + 128] + b[lane + 128]);
}

// ---------------- points2img scatter + 2x downsample ----------------
__global__ void k_scatter(const float* __restrict__ pos, int* __restrict__ img)
{
    int t = blockIdx.x * 256 + threadIdx.x;
    int b = t / NPTS, n = t - b * NPTS;
    int x = (int)pos[(size_t)t * 2];
    int y = (int)pos[(size_t)t * 2 + 1];
    img[(size_t)b * NPTS + y * 112 + x] = n;
}

__global__ void k_down(const int* __restrict__ img, int* __restrict__ idxa)
{
    int q = blockIdx.x * 256 + threadIdx.x;
    int b = q / N2, p2 = q - b * N2;
    int r = p2 / 56, c = p2 - r * 56;
    idxa[q] = img[(size_t)b * NPTS + (2 * r) * 112 + 2 * c];
}

// ---------------- transpose lin_W -> bf16 linT[384][6144] ----------------
__global__ __launch_bounds__(256) void k_linT(const float* __restrict__ W, ushort_t* __restrict__ T)
{
    __shared__ float tile[64][65];
    int k0 = blockIdx.x * 64, n0 = blockIdx.y * 64;
    for (int s = 0; s < 16; ++s) {
        int id = threadIdx.x + s * 256;
        int i = id >> 6, j = id & 63;
        tile[i][j] = W[(size_t)(k0 + i) * 384 + n0 + j];
    }
    __syncthreads();
    for (int s = 0; s < 16; ++s) {
        int id = threadIdx.x + s * 256;
        int jj = id >> 6, ii = id & 63;
        T[(size_t)(n0 + jj) * 6144 + k0 + ii] = f2bf(tile[ii][jj]);
    }
}

// ---------------- precompute f1W MFMA B-fragments: frag[ks][w][lane][j] ----------------
__global__ __launch_bounds__(256) void k_prep(const float* __restrict__ f1W, ushort_t* __restrict__ frag)
{
    int t = blockIdx.x * 256 + threadIdx.x;   // 12288 total
    int j = t & 7;
    int lane = (t >> 3) & 63;
    int w = (t >> 9) & 3;
    int ks = t >> 11;
    int k = ks * 32 + (lane >> 4) * 8 + j;
    int o = w * 16 + (lane & 15);
    frag[t] = f2bf(f1W[k * 64 + o]);
}

// ---------------- per-point: sampling + weights + agg build ----------------
__global__ __launch_bounds__(256) void k_point(
    const float* __restrict__ pos, const float* __restrict__ maskp,
    const int* __restrict__ massign, const int* __restrict__ memidx,
    const float* __restrict__ cmaskp, const ushort_t* __restrict__ featn,
    const int* __restrict__ idxarr, const ushort_t* __restrict__ f1frag,
    const float* __restrict__ w1W, const float* __restrict__ w1b,
    const float* __restrict__ lng, const float* __restrict__ lnb,
    const float* __restrict__ f1b,
    const float* __restrict__ f2W, const float* __restrict__ f2b,
    ushort_t* __restrict__ agg, float* __restrict__ outbuf, int p0)
{
    __shared__ double sc[128];
    __shared__ int memv[128];
    __shared__ double rs2[2];
    __shared__ int ri2[2];
    __shared__ int mcat[4];
    __shared__ float fg[4][200];
    __shared__ __align__(16) ushort_t frelb[4][200];
    __shared__ float prel[4][2];
    __shared__ float wsm[4][32];
    __shared__ float gpart[4][4];
    __shared__ float fwv[4];
    __shared__ float pd[2];

    int point = p0 + blockIdx.x;
    int b = point / N2;
    int tid = threadIdx.x;
    int wave = tid >> 6, lane = tid & 63;
    int l15 = lane & 15, l4 = lane >> 4;
    int idx_pt = idxarr[point];

    if (tid < 128) {
        int j = tid >> 4, i = tid & 15;
        int maj = massign[((size_t)b * NPTS + idx_pt) * 8 + j];
        size_t roff = ((size_t)b * KCL + maj) * 16 + i;
        int mv = memidx[roff];
        float cv = cmaskp[roff];
        if (mv == idx_pt) cv = 0.f;
        float pr = fmaxf(cv, 1e-5f);
        uint32 gi = (uint32)point * 128u + (uint32)tid;
        uint32 y0, y1;
        threefry(0u, gi, y0, y1);
        uint32 bits = y0 ^ y1;
        union { uint32 u; float f; } cu; cu.u = (bits >> 9) | 0x3f800000u;
        float u = cu.f - 1.0f;
        double gum = -log(-log((double)u + 1e-20) + 1e-20);
        sc[tid] = log((double)pr) + gum;
        memv[tid] = mv;
    }
    if (tid == 128) {
        pd[0] = pos[((size_t)b * NPTS + idx_pt) * 2];
        pd[1] = pos[((size_t)b * NPTS + idx_pt) * 2 + 1];
    }
    if (tid == 129) outbuf[OUT_MASK_OFF + point] = maskp[(size_t)b * NPTS + idx_pt];
    __syncthreads();
    if (tid < 2) outbuf[(size_t)point * 2 + tid] = floorf(pd[tid] * 0.5f);

    // top-3 (desc, ties -> lower index): wave-level argmax
    for (int pass = 0; pass < 3; ++pass) {
        double s = (tid < 128) ? sc[tid] : -1.0e300;
        int si = (tid < 128) ? tid : 0;
        for (int d = 32; d >= 1; d >>= 1) {
            double s2 = __shfl_xor(s, d, 64);
            int i2 = __shfl_xor(si, d, 64);
            if (s2 > s || (s2 == s && i2 < si)) { s = s2; si = i2; }
        }
        if (lane == 0 && wave < 2) { rs2[wave] = s; ri2[wave] = si; }
        __syncthreads();
        if (tid == 0) {
            int w = (rs2[1] > rs2[0] || (rs2[1] == rs2[0] && ri2[1] < ri2[0])) ? ri2[1] : ri2[0];
            mcat[pass] = memv[w];
            sc[w] = -1.0e300;
        }
        __syncthreads();
    }
    if (tid == 0) mcat[3] = idx_pt;
    __syncthreads();

    // gather 4 neighbor rows of feat_n (bf16 -> f32 LDS) + pos_rel
    {
        size_t rbase = ((size_t)b * NPTS + mcat[wave]) * CC;
        for (int jj = 0; jj < 3; ++jj) {
            int c = lane + jj * 64;
            fg[wave][c] = bf2f(featn[rbase + c]);
        }
        if (lane == 0) {
            prel[wave][0] = pos[((size_t)b * NPTS + mcat[wave]) * 2]     - pd[0];
            prel[wave][1] = pos[((size_t)b * NPTS + mcat[wave]) * 2 + 1] - pd[1];
        }
    }
    __syncthreads();

    // build feat_rel bf16 (rows 0..3), padded stride 200
    for (int it = 0; it < 3; ++it) {
        int idx = it * 256 + tid;          // < 768
        int mm = idx / 192, cq = idx - mm * 192;
        frelb[mm][cq] = f2bf(fg[mm][cq] - fg[3][cq]);
    }

    // pos MLP: (pos_rel @ w1) -> LN(32) -> gelu   (waves 0,1)
    if (tid < 128) {
        int mm = tid >> 5, kk = tid & 31;
        float pre = prel[mm][0] * w1W[kk] + prel[mm][1] * w1W[32 + kk] + w1b[kk];
        float s = pre;
        for (int d = 16; d >= 1; d >>= 1) s += __shfl_xor(s, d, 32);
        float mu = s * (1.f / 32.f);
        float dv = pre - mu;
        float vs = dv * dv;
        for (int d = 16; d >= 1; d >>= 1) vs += __shfl_xor(vs, d, 32);
        float var = vs * (1.f / 32.f);
        float nv = dv / sqrtf(var + 1e-5f) * lng[kk] + lnb[kk];
        wsm[mm][kk] = gelu_exact(nv);
    }
    __syncthreads();

    // feature gate via MFMA: h = feat_rel(4x192) @ f1W(192x64); wave w owns o-tile w*16
    {
        f32x4 acc = (f32x4){0.f, 0.f, 0.f, 0.f};
#pragma unroll
        for (int ks = 0; ks < 6; ++ks) {
            short8 av;
            if (l15 < 4) av = *(const short8*)(&frelb[l15][ks * 32 + l4 * 8]);
            else av = (short8){0,0,0,0,0,0,0,0};
            short8 bv = *(const short8*)(f1frag + ((size_t)(ks * 4 + wave) * 64 + lane) * 8);
            acc = __builtin_amdgcn_mfma_f32_16x16x32_bf16(av, bv, acc, 0, 0, 0);
        }
        float p0_ = 0.f, p1_ = 0.f, p2_ = 0.f, p3_ = 0.f;
        if (l4 == 0) {
            int o = wave * 16 + l15;
            float fb = f1b[o], fw2 = f2W[o];
            p0_ = gelu_exact(acc[0] + fb) * fw2;
            p1_ = gelu_exact(acc[1] + fb) * fw2;
            p2_ = gelu_exact(acc[2] + fb) * fw2;
            p3_ = gelu_exact(acc[3] + fb) * fw2;
        }
        for (int d = 8; d >= 1; d >>= 1) {
            p0_ += __shfl_xor(p0_, d, 64);
            p1_ += __shfl_xor(p1_, d, 64);
            p2_ += __shfl_xor(p2_, d, 64);
            p3_ += __shfl_xor(p3_, d, 64);
        }
        if (lane == 0) { gpart[wave][0] = p0_; gpart[wave][1] = p1_; gpart[wave][2] = p2_; gpart[wave][3] = p3_; }
    }
    __syncthreads();
    if (tid < 4) {
        float t = gpart[0][tid] + gpart[1][tid] + gpart[2][tid] + gpart[3][tid] + f2b[0];
        fwv[tid] = 1.f / (1.f + expf(-t));
    }
    __syncthreads();
    if (tid < 128) { int mm = tid >> 5, kk = tid & 31; wsm[mm][kk] *= fwv[mm]; }
    __syncthreads();

    // agg[k][c] = sum_m w[m][k] * feat_g[m][c]  -> bf16
    size_t abase = (size_t)blockIdx.x * 6144;
    for (int ii = 0; ii < 24; ++ii) {
        int kc = ii * 256 + tid;
        int kq = kc / 192;
        int cq = kc - kq * 192;
        float v = wsm[0][kq] * fg[0][cq] + wsm[1][kq] * fg[1][cq]
                + wsm[2][kq] * fg[2][cq] + wsm[3][kq] * fg[3][cq];
        agg[abase + kc] = f2bf(v);
    }
}

// ---------------- GEMM: (cnt x 6144) @ (6144 x 384), bf16 MFMA, global_load_lds ----------------
__global__ __launch_bounds__(256) void k_gemm(const ushort_t* __restrict__ A,
    const ushort_t* __restrict__ BT, const float* __restrict__ bias,
    float* __restrict__ out, int p0)
{
    __shared__ __align__(16) ushort_t As[128][32];
    __shared__ __align__(16) ushort_t Bs[128][32];
    int tid = threadIdx.x;
    int wave = tid >> 6, lane = tid & 63;
    int l15 = lane & 15, l4 = lane >> 4;
    int m0 = blockIdx.x * 128;
    int n0 = blockIdx.y * 128;
    int wr = (wave >> 1) * 64, wc = (wave & 1) * 64;

    int srow = lane >> 2;            // 0..15
    int scol = (lane & 3) * 8;       // ushort offset
    const ushort_t* ga0 = A  + (size_t)(m0 + wave * 32 + srow) * 6144 + scol;
    const ushort_t* gb0 = BT + (size_t)(n0 + wave * 32 + srow) * 6144 + scol;
    ushort_t* la0 = &As[wave * 32][0];
    ushort_t* lb0 = &Bs[wave * 32][0];

    f32x4 acc[4][4];
#pragma unroll
    for (int mi = 0; mi < 4; ++mi)
#pragma unroll
        for (int ni = 0; ni < 4; ++ni)
            acc[mi][ni] = (f32x4){0.f, 0.f, 0.f, 0.f};

    for (int k0 = 0; k0 < 6144; k0 += 32) {
        gld16(ga0 + k0,             la0);
        gld16(ga0 + k0 + 16 * 6144, la0 + 16 * 32);
        gld16(gb0 + k0,             lb0);
        gld16(gb0 + k0 + 16 * 6144, lb0 + 16 * 32);
        __syncthreads();
        short8 av[4], bv[4];
#pragma unroll
        for (int mi = 0; mi < 4; ++mi) av[mi] = *(const short8*)(&As[wr + mi * 16 + l15][l4 * 8]);
#pragma unroll
        for (int ni = 0; ni < 4; ++ni) bv[ni] = *(const short8*)(&Bs[wc + ni * 16 + l15][l4 * 8]);
#pragma unroll
        for (int mi = 0; mi < 4; ++mi)
#pragma unroll
            for (int ni = 0; ni < 4; ++ni)
                acc[mi][ni] = __builtin_amdgcn_mfma_f32_16x16x32_bf16(av[mi], bv[ni], acc[mi][ni], 0, 0, 0);
        __syncthreads();
    }

#pragma unroll
    for (int mi = 0; mi < 4; ++mi)
#pragma unroll
        for (int ni = 0; ni < 4; ++ni)
#pragma unroll
            for (int r = 0; r < 4; ++r) {
                int rr = wr + mi * 16 + l4 * 4 + r;
                int ccol = wc + ni * 16 + l15;
                out[(size_t)(p0 + m0 + rr) * 384 + n0 + ccol] = acc[mi][ni][r] + bias[n0 + ccol];
            }
}

extern "C" void kernel_launch(void* const* d_in, const int* in_sizes, int n_in,
                              void* d_out, int out_size, void* d_ws, size_t ws_size,
                              hipStream_t stream)
{
    const float* pos      = (const float*)d_in[0];
    const float* feat     = (const float*)d_in[1];
    const float* maskp    = (const float*)d_in[2];
    const int*   massign  = (const int*)d_in[4];
    const int*   memidx   = (const int*)d_in[5];
    const float* cmaskp   = (const float*)d_in[9];
    const float* norm_g   = (const float*)d_in[10];
    const float* norm_b   = (const float*)d_in[11];
    const float* w1W      = (const float*)d_in[12];
    const float* w1b      = (const float*)d_in[13];
    const float* lng      = (const float*)d_in[14];
    const float* lnb      = (const float*)d_in[15];
    const float* f1W      = (const float*)d_in[16];
    const float* f1b      = (const float*)d_in[17];
    const float* f2W      = (const float*)d_in[18];
    const float* f2b      = (const float*)d_in[19];
    const float* linW     = (const float*)d_in[20];
    const float* linb     = (const float*)d_in[21];

    char* ws = (char*)d_ws;
    ushort_t* featn  = (ushort_t*)(ws);
    int* img         = (int*)(ws + 38535168);
    int* idxa        = (int*)(ws + 38936576);
    ushort_t* linT   = (ushort_t*)(ws + 39036928);
    ushort_t* f1frag = (ushort_t*)(ws + 43755520);   // 12288 ushorts = 24576 bytes
    ushort_t* agg    = (ushort_t*)(ws + 43780096);   // FIX: was +43767808, overlapped f1frag

    size_t avail = ws_size > 43780096 ? ws_size - 43780096 : 0;
    long long slabM = (long long)(avail / 12288);
    slabM &= ~127LL;
    if (slabM > TOTPTS) slabM = TOTPTS;
    if (slabM < 128) slabM = 128;

    k_ln<<<TOTPTS, 256, 0, stream>>>(feat, norm_g, norm_b, featn);
    hipMemsetAsync(img, 0, 401408, stream);
    k_scatter<<<392, 256, 0, stream>>>(pos, img);
    k_down<<<98, 256, 0, stream>>>(img, idxa);
    k_linT<<<dim3(96, 6), 256, 0, stream>>>(linW, linT);
    k_prep<<<48, 256, 0, stream>>>(f1W, f1frag);

    float* outF = (float*)d_out;
    for (int p0 = 0; p0 < TOTPTS; p0 += (int)slabM) {
        int cnt = TOTPTS - p0; if (cnt > (int)slabM) cnt = (int)slabM;
        k_point<<<cnt, 256, 0, stream>>>(pos, maskp, massign, memidx, cmaskp, featn, idxa, f1frag,
                w1W, w1b, lng, lnb, f1b, f2W, f2b, agg, outF, p0);
        k_gemm<<<dim3(cnt / 128, 3), 256, 0, stream>>>(agg, linT, linb, outF + OUT_FEAT_OFF, p0);
    }
}

// Round 5
// 433.995 us; speedup vs baseline: 1.3251x; 1.1407x over previous
//
#include <hip/hip_runtime.h>

typedef unsigned short ushort_t;
typedef unsigned char uchar;
typedef unsigned int uint32;
typedef __attribute__((ext_vector_type(8))) short short8;
typedef __attribute__((ext_vector_type(4))) float f32x4;
typedef __attribute__((ext_vector_type(4))) unsigned int u32x4;

#define BATCH 8
#define NPTS 12544
#define CC 192
#define KCL 784
#define N2 3136
#define TOTPTS 25088        // BATCH*N2
#define OUT_FEAT_OFF 50176
#define OUT_MASK_OFF 9683968

__device__ __forceinline__ ushort_t f2bf(float f) {
    union { float f; uint32 u; } v; v.f = f;
    uint32 u = v.u;
    uint32 r = (u + 0x7FFFu + ((u >> 16) & 1u)) >> 16;
    return (ushort_t)r;
}
__device__ __forceinline__ float bf2f(ushort_t h) {
    union { uint32 u; float f; } v; v.u = ((uint32)h) << 16;
    return v.f;
}
__device__ __forceinline__ float gelu_exact(float x) {
    return 0.5f * x * (1.f + erff(x * 0.70710678118654752f));
}
__device__ __forceinline__ uchar f2e4m3(float f) {
    return (uchar)(__builtin_amdgcn_cvt_pk_fp8_f32(f, f, 0, false) & 0xFF);
}

__device__ __forceinline__ void gld16(const void* g, void* l) {
    __builtin_amdgcn_global_load_lds((const __attribute__((address_space(1))) void*)g,
                                     (__attribute__((address_space(3))) void*)l, 16, 0, 0);
}

// JAX threefry2x32 with key = (0, 42)
__device__ __forceinline__ void threefry(uint32 x0, uint32 x1, uint32& y0, uint32& y1) {
    const uint32 k0 = 0u, k1 = 42u;
    const uint32 k2 = 0u ^ 42u ^ 0x1BD11BDAu;
#define ROT(v,r) (((v) << (r)) | ((v) >> (32 - (r))))
#define RND(r) { x0 += x1; x1 = ROT(x1, r); x1 ^= x0; }
    x0 += k0; x1 += k1;
    RND(13) RND(15) RND(26) RND(6)
    x0 += k1; x1 += k2 + 1u;
    RND(17) RND(29) RND(16) RND(24)
    x0 += k2; x1 += k0 + 2u;
    RND(13) RND(15) RND(26) RND(6)
    x0 += k0; x1 += k1 + 3u;
    RND(17) RND(29) RND(16) RND(24)
    x0 += k1; x1 += k2 + 4u;
    RND(13) RND(15) RND(26) RND(6)
    x0 += k2; x1 += k0 + 5u;
    y0 = x0; y1 = x1;
#undef RND
#undef ROT
}

// ---------------- LayerNorm of feat -> bf16 ----------------
__global__ __launch_bounds__(256) void k_ln(const float* __restrict__ x,
        const float* __restrict__ g, const float* __restrict__ b,
        ushort_t* __restrict__ y)
{
    int row = blockIdx.x * 4 + (threadIdx.x >> 6);
    int lane = threadIdx.x & 63;
    const float* xr = x + (size_t)row * CC;
    float v0 = xr[lane], v1 = xr[lane + 64], v2 = xr[lane + 128];
    float s = v0 + v1 + v2;
    for (int d = 32; d >= 1; d >>= 1) s += __shfl_xor(s, d, 64);
    float mu = s * (1.f / 192.f);
    float d0 = v0 - mu, d1 = v1 - mu, d2 = v2 - mu;
    float q = d0 * d0 + d1 * d1 + d2 * d2;
    for (int d = 32; d >= 1; d >>= 1) q += __shfl_xor(q, d, 64);
    float rstd = 1.f / sqrtf(q * (1.f / 192.f) + 1e-5f);
    ushort_t* yr = y + (size_t)row * CC;
    yr[lane]       = f2bf(d0 * rstd * g[lane]       + b[lane]);
    yr[lane + 64]  = f2bf(d1 * rstd * g[lane + 64]  + b[lane + 64]);
    yr[lane + 128] = f2bf(d2 * rstd * g[lane + 128] + b[lane + 128]);
}

// ---------------- points2img scatter + 2x downsample ----------------
__global__ void k_scatter(const float* __restrict__ pos, int* __restrict__ img)
{
    int t = blockIdx.x * 256 + threadIdx.x;
    int b = t / NPTS, n = t - b * NPTS;
    int x = (int)pos[(size_t)t * 2];
    int y = (int)pos[(size_t)t * 2 + 1];
    img[(size_t)b * NPTS + y * 112 + x] = n;
}

__global__ void k_down(const int* __restrict__ img, int* __restrict__ idxa)
{
    int q = blockIdx.x * 256 + threadIdx.x;
    int b = q / N2, p2 = q - b * N2;
    int r = p2 / 56, c = p2 - r * 56;
    idxa[q] = img[(size_t)b * NPTS + (2 * r) * 112 + 2 * c];
}

// ---------------- transpose lin_W -> fp8 linT[384][6144] ----------------
__global__ __launch_bounds__(256) void k_linT(const float* __restrict__ W, uchar* __restrict__ T)
{
    __shared__ float tile[64][65];
    int k0 = blockIdx.x * 64, n0 = blockIdx.y * 64;
    for (int s = 0; s < 16; ++s) {
        int id = threadIdx.x + s * 256;
        int i = id >> 6, j = id & 63;
        tile[i][j] = W[(size_t)(k0 + i) * 384 + n0 + j];
    }
    __syncthreads();
    for (int s = 0; s < 16; ++s) {
        int id = threadIdx.x + s * 256;
        int jj = id >> 6, ii = id & 63;
        T[(size_t)(n0 + jj) * 6144 + k0 + ii] = f2e4m3(tile[ii][jj]);
    }
}

// ---------------- precompute f1W MFMA B-fragments (bf16): frag[ks][w][lane][j] ----------------
__global__ __launch_bounds__(256) void k_prep(const float* __restrict__ f1W, ushort_t* __restrict__ frag)
{
    int t = blockIdx.x * 256 + threadIdx.x;   // 12288 total
    int j = t & 7;
    int lane = (t >> 3) & 63;
    int w = (t >> 9) & 3;
    int ks = t >> 11;
    int k = ks * 32 + (lane >> 4) * 8 + j;
    int o = w * 16 + (lane & 15);
    frag[t] = f2bf(f1W[k * 64 + o]);
}

// ---------------- per-point: sampling + weights + agg build (fp8) ----------------
__global__ __launch_bounds__(256) void k_point(
    const float* __restrict__ pos, const float* __restrict__ maskp,
    const int* __restrict__ massign, const int* __restrict__ memidx,
    const float* __restrict__ cmaskp, const ushort_t* __restrict__ featn,
    const int* __restrict__ idxarr, const ushort_t* __restrict__ f1frag,
    const float* __restrict__ w1W, const float* __restrict__ w1b,
    const float* __restrict__ lng, const float* __restrict__ lnb,
    const float* __restrict__ f1b,
    const float* __restrict__ f2W, const float* __restrict__ f2b,
    uchar* __restrict__ agg, float* __restrict__ outbuf, int p0)
{
    __shared__ double sc[128];
    __shared__ int memv[128];
    __shared__ double rs2[2];
    __shared__ int ri2[2];
    __shared__ int mcat[4];
    __shared__ float fg[4][200];
    __shared__ __align__(16) ushort_t frelb[4][200];
    __shared__ float prel[4][2];
    __shared__ float wsm[4][32];
    __shared__ float gpart[4][4];
    __shared__ float fwv[4];
    __shared__ float pd[2];

    int point = p0 + blockIdx.x;
    int b = point / N2;
    int tid = threadIdx.x;
    int wave = tid >> 6, lane = tid & 63;
    int l15 = lane & 15, l4 = lane >> 4;
    int idx_pt = idxarr[point];

    if (tid < 128) {
        int j = tid >> 4, i = tid & 15;
        int maj = massign[((size_t)b * NPTS + idx_pt) * 8 + j];
        size_t roff = ((size_t)b * KCL + maj) * 16 + i;
        int mv = memidx[roff];
        float cv = cmaskp[roff];
        if (mv == idx_pt) cv = 0.f;
        float pr = fmaxf(cv, 1e-5f);
        uint32 gi = (uint32)point * 128u + (uint32)tid;
        uint32 y0, y1;
        threefry(0u, gi, y0, y1);
        uint32 bits = y0 ^ y1;
        union { uint32 u; float f; } cu; cu.u = (bits >> 9) | 0x3f800000u;
        float u = cu.f - 1.0f;
        double gum = -log(-log((double)u + 1e-20) + 1e-20);
        sc[tid] = log((double)pr) + gum;
        memv[tid] = mv;
    }
    if (tid == 128) {
        pd[0] = pos[((size_t)b * NPTS + idx_pt) * 2];
        pd[1] = pos[((size_t)b * NPTS + idx_pt) * 2 + 1];
    }
    if (tid == 129) outbuf[OUT_MASK_OFF + point] = maskp[(size_t)b * NPTS + idx_pt];
    __syncthreads();
    if (tid < 2) outbuf[(size_t)point * 2 + tid] = floorf(pd[tid] * 0.5f);

    // top-3 (desc, ties -> lower index): wave-level argmax
    for (int pass = 0; pass < 3; ++pass) {
        double s = (tid < 128) ? sc[tid] : -1.0e300;
        int si = (tid < 128) ? tid : 0;
        for (int d = 32; d >= 1; d >>= 1) {
            double s2 = __shfl_xor(s, d, 64);
            int i2 = __shfl_xor(si, d, 64);
            if (s2 > s || (s2 == s && i2 < si)) { s = s2; si = i2; }
        }
        if (lane == 0 && wave < 2) { rs2[wave] = s; ri2[wave] = si; }
        __syncthreads();
        if (tid == 0) {
            int w = (rs2[1] > rs2[0] || (rs2[1] == rs2[0] && ri2[1] < ri2[0])) ? ri2[1] : ri2[0];
            mcat[pass] = memv[w];
            sc[w] = -1.0e300;
        }
        __syncthreads();
    }
    if (tid == 0) mcat[3] = idx_pt;
    __syncthreads();

    // gather 4 neighbor rows of feat_n (bf16 -> f32 LDS) + pos_rel
    {
        size_t rbase = ((size_t)b * NPTS + mcat[wave]) * CC;
        for (int jj = 0; jj < 3; ++jj) {
            int c = lane + jj * 64;
            fg[wave][c] = bf2f(featn[rbase + c]);
        }
        if (lane == 0) {
            prel[wave][0] = pos[((size_t)b * NPTS + mcat[wave]) * 2]     - pd[0];
            prel[wave][1] = pos[((size_t)b * NPTS + mcat[wave]) * 2 + 1] - pd[1];
        }
    }
    __syncthreads();

    // build feat_rel bf16 (rows 0..3), padded stride 200
    for (int it = 0; it < 3; ++it) {
        int idx = it * 256 + tid;          // < 768
        int mm = idx / 192, cq = idx - mm * 192;
        frelb[mm][cq] = f2bf(fg[mm][cq] - fg[3][cq]);
    }

    // pos MLP: (pos_rel @ w1) -> LN(32) -> gelu   (waves 0,1)
    if (tid < 128) {
        int mm = tid >> 5, kk = tid & 31;
        float pre = prel[mm][0] * w1W[kk] + prel[mm][1] * w1W[32 + kk] + w1b[kk];
        float s = pre;
        for (int d = 16; d >= 1; d >>= 1) s += __shfl_xor(s, d, 32);
        float mu = s * (1.f / 32.f);
        float dv = pre - mu;
        float vs = dv * dv;
        for (int d = 16; d >= 1; d >>= 1) vs += __shfl_xor(vs, d, 32);
        float var = vs * (1.f / 32.f);
        float nv = dv / sqrtf(var + 1e-5f) * lng[kk] + lnb[kk];
        wsm[mm][kk] = gelu_exact(nv);
    }
    __syncthreads();

    // feature gate via MFMA: h = feat_rel(4x192) @ f1W(192x64); wave w owns o-tile w*16
    {
        f32x4 acc = (f32x4){0.f, 0.f, 0.f, 0.f};
#pragma unroll
        for (int ks = 0; ks < 6; ++ks) {
            short8 av;
            if (l15 < 4) av = *(const short8*)(&frelb[l15][ks * 32 + l4 * 8]);
            else av = (short8){0,0,0,0,0,0,0,0};
            short8 bv = *(const short8*)(f1frag + ((size_t)(ks * 4 + wave) * 64 + lane) * 8);
            acc = __builtin_amdgcn_mfma_f32_16x16x32_bf16(av, bv, acc, 0, 0, 0);
        }
        float p0_ = 0.f, p1_ = 0.f, p2_ = 0.f, p3_ = 0.f;
        if (l4 == 0) {
            int o = wave * 16 + l15;
            float fb = f1b[o], fw2 = f2W[o];
            p0_ = gelu_exact(acc[0] + fb) * fw2;
            p1_ = gelu_exact(acc[1] + fb) * fw2;
            p2_ = gelu_exact(acc[2] + fb) * fw2;
            p3_ = gelu_exact(acc[3] + fb) * fw2;
        }
        for (int d = 8; d >= 1; d >>= 1) {
            p0_ += __shfl_xor(p0_, d, 64);
            p1_ += __shfl_xor(p1_, d, 64);
            p2_ += __shfl_xor(p2_, d, 64);
            p3_ += __shfl_xor(p3_, d, 64);
        }
        if (lane == 0) { gpart[wave][0] = p0_; gpart[wave][1] = p1_; gpart[wave][2] = p2_; gpart[wave][3] = p3_; }
    }
    __syncthreads();
    if (tid < 4) {
        float t = gpart[0][tid] + gpart[1][tid] + gpart[2][tid] + gpart[3][tid] + f2b[0];
        fwv[tid] = 1.f / (1.f + expf(-t));
    }
    __syncthreads();
    if (tid < 128) { int mm = tid >> 5, kk = tid & 31; wsm[mm][kk] *= fwv[mm]; }
    __syncthreads();

    // agg[k][c] = sum_m w[m][k] * feat_g[m][c]  -> fp8 e4m3 (pairs, never straddle a c-row)
    size_t abase = (size_t)point * 6144;
    for (int ii = 0; ii < 12; ++ii) {
        int kc = (ii * 256 + tid) * 2;
        int kq = kc / 192;
        int cq = kc - kq * 192;
        float v0 = wsm[0][kq] * fg[0][cq] + wsm[1][kq] * fg[1][cq]
                 + wsm[2][kq] * fg[2][cq] + wsm[3][kq] * fg[3][cq];
        float v1 = wsm[0][kq] * fg[0][cq + 1] + wsm[1][kq] * fg[1][cq + 1]
                 + wsm[2][kq] * fg[2][cq + 1] + wsm[3][kq] * fg[3][cq + 1];
        int pk = __builtin_amdgcn_cvt_pk_fp8_f32(v0, v1, 0, false);
        *(unsigned short*)(agg + abase + kc) = (unsigned short)(pk & 0xFFFF);
    }
}

// ---------------- GEMM: (cnt x 6144) @ (6144 x 384), fp8 MFMA, BK=64, swizzled ----------------
__global__ __launch_bounds__(256) void k_gemm(const uchar* __restrict__ A,
    const uchar* __restrict__ BT, const float* __restrict__ bias,
    float* __restrict__ out, int p0)
{
    __shared__ __align__(16) uchar As[128][64];
    __shared__ __align__(16) uchar Bs[128][64];
    uchar* AsF = &As[0][0];
    uchar* BsF = &Bs[0][0];
    int tid = threadIdx.x;
    int wave = tid >> 6, lane = tid & 63;
    int l15 = lane & 15, l4 = lane >> 4;
    int m0 = blockIdx.x * 128;
    int n0 = blockIdx.y * 128;
    int wr = (wave >> 1) * 64, wc = (wave & 1) * 64;

    // staging: it in {0,1}; row = it*64 + wave*16 + (lane>>2); slot s = lane&3;
    // LDS dest linear (wave-uniform base + lane*16); global source pre-swizzled: col16 = s ^ (row&3)
    int rr0 = wave * 16 + (lane >> 2);
    int sc0 = (((lane & 3) ^ ((lane >> 2) & 3)) * 16);
    const uchar* gaA0 = A  + (size_t)(p0 + m0 + rr0) * 6144 + sc0;
    const uchar* gaA1 = A  + (size_t)(p0 + m0 + rr0 + 64) * 6144 + sc0;
    const uchar* gaB0 = BT + (size_t)(n0 + rr0) * 6144 + sc0;
    const uchar* gaB1 = BT + (size_t)(n0 + rr0 + 64) * 6144 + sc0;
    uchar* lA0 = AsF + wave * 1024;
    uchar* lA1 = AsF + 4096 + wave * 1024;
    uchar* lB0 = BsF + wave * 1024;
    uchar* lB1 = BsF + 4096 + wave * 1024;

    f32x4 acc[4][4];
#pragma unroll
    for (int mi = 0; mi < 4; ++mi)
#pragma unroll
        for (int ni = 0; ni < 4; ++ni)
            acc[mi][ni] = (f32x4){0.f, 0.f, 0.f, 0.f};

    for (int k0 = 0; k0 < 6144; k0 += 64) {
        gld16(gaA0 + k0, lA0);
        gld16(gaA1 + k0, lA1);
        gld16(gaB0 + k0, lB0);
        gld16(gaB1 + k0, lB1);
        __syncthreads();
        long long av[4][2], bv[4][2];
#pragma unroll
        for (int mi = 0; mi < 4; ++mi) {
            int row = wr + mi * 16 + l15;
#pragma unroll
            for (int ks = 0; ks < 2; ++ks) {
                int slot = (ks * 2 + (l4 >> 1)) ^ (l15 & 3);
                av[mi][ks] = *(const long long*)(AsF + row * 64 + slot * 16 + (l4 & 1) * 8);
            }
        }
#pragma unroll
        for (int ni = 0; ni < 4; ++ni) {
            int row = wc + ni * 16 + l15;
#pragma unroll
            for (int ks = 0; ks < 2; ++ks) {
                int slot = (ks * 2 + (l4 >> 1)) ^ (l15 & 3);
                bv[ni][ks] = *(const long long*)(BsF + row * 64 + slot * 16 + (l4 & 1) * 8);
            }
        }
#pragma unroll
        for (int mi = 0; mi < 4; ++mi)
#pragma unroll
            for (int ni = 0; ni < 4; ++ni) {
                acc[mi][ni] = __builtin_amdgcn_mfma_f32_16x16x32_fp8_fp8(av[mi][0], bv[ni][0], acc[mi][ni], 0, 0, 0);
                acc[mi][ni] = __builtin_amdgcn_mfma_f32_16x16x32_fp8_fp8(av[mi][1], bv[ni][1], acc[mi][ni], 0, 0, 0);
            }
        __syncthreads();
    }

#pragma unroll
    for (int mi = 0; mi < 4; ++mi)
#pragma unroll
        for (int ni = 0; ni < 4; ++ni)
#pragma unroll
            for (int r = 0; r < 4; ++r) {
                int rr = wr + mi * 16 + l4 * 4 + r;
                int ccol = wc + ni * 16 + l15;
                out[(size_t)(p0 + m0 + rr) * 384 + n0 + ccol] = acc[mi][ni][r] + bias[n0 + ccol];
            }
}

extern "C" void kernel_launch(void* const* d_in, const int* in_sizes, int n_in,
                              void* d_out, int out_size, void* d_ws, size_t ws_size,
                              hipStream_t stream)
{
    const float* pos      = (const float*)d_in[0];
    const float* feat     = (const float*)d_in[1];
    const float* maskp    = (const float*)d_in[2];
    const int*   massign  = (const int*)d_in[4];
    const int*   memidx   = (const int*)d_in[5];
    const float* cmaskp   = (const float*)d_in[9];
    const float* norm_g   = (const float*)d_in[10];
    const float* norm_b   = (const float*)d_in[11];
    const float* w1W      = (const float*)d_in[12];
    const float* w1b      = (const float*)d_in[13];
    const float* lng      = (const float*)d_in[14];
    const float* lnb      = (const float*)d_in[15];
    const float* f1W      = (const float*)d_in[16];
    const float* f1b      = (const float*)d_in[17];
    const float* f2W      = (const float*)d_in[18];
    const float* f2b      = (const float*)d_in[19];
    const float* linW     = (const float*)d_in[20];
    const float* linb     = (const float*)d_in[21];

    char* ws = (char*)d_ws;
    ushort_t* featn  = (ushort_t*)(ws);                 // 38,535,168 B
    int* img         = (int*)(ws + 38535168);           //    401,408 B
    int* idxa        = (int*)(ws + 38936576);           //    100,352 B
    uchar* linT      = (uchar*)(ws + 39036928);         //  2,359,296 B (fp8)
    ushort_t* f1frag = (ushort_t*)(ws + 41396224);      //     24,576 B
    uchar* agg       = (uchar*)(ws + 41420800);         // up to 154,140,672 B (fp8)

    size_t avail = ws_size > 41420800 ? ws_size - 41420800 : 0;
    long long slabM = (long long)(avail / 6144);
    slabM &= ~127LL;
    if (slabM > TOTPTS) slabM = TOTPTS;
    if (slabM < 128) slabM = 128;

    k_ln<<<TOTPTS, 256, 0, stream>>>(feat, norm_g, norm_b, featn);
    hipMemsetAsync(img, 0, 401408, stream);
    k_scatter<<<392, 256, 0, stream>>>(pos, img);
    k_down<<<98, 256, 0, stream>>>(img, idxa);
    k_linT<<<dim3(96, 6), 256, 0, stream>>>(linW, linT);
    k_prep<<<48, 256, 0, stream>>>(f1W, f1frag);

    float* outF = (float*)d_out;
    for (int p0 = 0; p0 < TOTPTS; p0 += (int)slabM) {
        int cnt = TOTPTS - p0; if (cnt > (int)slabM) cnt = (int)slabM;
        k_point<<<cnt, 256, 0, stream>>>(pos, maskp, massign, memidx, cmaskp, featn, idxa, f1frag,
                w1W, w1b, lng, lnb, f1b, f2W, f2b, agg, outF, p0);
        k_gemm<<<dim3(cnt / 128, 3), 256, 0, stream>>>(agg, linT, linb, outF + OUT_FEAT_OFF, p0);
    }
}

// Round 6
// 344.622 us; speedup vs baseline: 1.6687x; 1.2593x over previous
//
#include <hip/hip_runtime.h>

typedef unsigned short ushort_t;
typedef unsigned char uchar;
typedef unsigned int uint32;
typedef __attribute__((ext_vector_type(8))) short short8;
typedef __attribute__((ext_vector_type(4))) float f32x4;
typedef __attribute__((ext_vector_type(4))) unsigned int u32x4;

#define BATCH 8
#define NPTS 12544
#define CC 192
#define KCL 784
#define N2 3136
#define TOTPTS 25088        // BATCH*N2
#define OUT_FEAT_OFF 50176
#define OUT_MASK_OFF 9683968

__device__ __forceinline__ ushort_t f2bf(float f) {
    union { float f; uint32 u; } v; v.f = f;
    uint32 u = v.u;
    uint32 r = (u + 0x7FFFu + ((u >> 16) & 1u)) >> 16;
    return (ushort_t)r;
}
__device__ __forceinline__ float bf2f(ushort_t h) {
    union { uint32 u; float f; } v; v.u = ((uint32)h) << 16;
    return v.f;
}
__device__ __forceinline__ float gelu_exact(float x) {
    return 0.5f * x * (1.f + erff(x * 0.70710678118654752f));
}
__device__ __forceinline__ uchar f2e4m3(float f) {
    return (uchar)(__builtin_amdgcn_cvt_pk_fp8_f32(f, f, 0, false) & 0xFF);
}

__device__ __forceinline__ void gld16(const void* g, void* l) {
    __builtin_amdgcn_global_load_lds((const __attribute__((address_space(1))) void*)g,
                                     (__attribute__((address_space(3))) void*)l, 16, 0, 0);
}

// JAX threefry2x32 with key = (0, 42)
__device__ __forceinline__ void threefry(uint32 x0, uint32 x1, uint32& y0, uint32& y1) {
    const uint32 k0 = 0u, k1 = 42u;
    const uint32 k2 = 0u ^ 42u ^ 0x1BD11BDAu;
#define ROT(v,r) (((v) << (r)) | ((v) >> (32 - (r))))
#define RND(r) { x0 += x1; x1 = ROT(x1, r); x1 ^= x0; }
    x0 += k0; x1 += k1;
    RND(13) RND(15) RND(26) RND(6)
    x0 += k1; x1 += k2 + 1u;
    RND(17) RND(29) RND(16) RND(24)
    x0 += k2; x1 += k0 + 2u;
    RND(13) RND(15) RND(26) RND(6)
    x0 += k0; x1 += k1 + 3u;
    RND(17) RND(29) RND(16) RND(24)
    x0 += k1; x1 += k2 + 4u;
    RND(13) RND(15) RND(26) RND(6)
    x0 += k2; x1 += k0 + 5u;
    y0 = x0; y1 = x1;
#undef RND
#undef ROT
}

// ---------------- LayerNorm of feat -> bf16 ----------------
__global__ __launch_bounds__(256) void k_ln(const float* __restrict__ x,
        const float* __restrict__ g, const float* __restrict__ b,
        ushort_t* __restrict__ y)
{
    int row = blockIdx.x * 4 + (threadIdx.x >> 6);
    int lane = threadIdx.x & 63;
    const float* xr = x + (size_t)row * CC;
    float v0 = xr[lane], v1 = xr[lane + 64], v2 = xr[lane + 128];
    float s = v0 + v1 + v2;
    for (int d = 32; d >= 1; d >>= 1) s += __shfl_xor(s, d, 64);
    float mu = s * (1.f / 192.f);
    float d0 = v0 - mu, d1 = v1 - mu, d2 = v2 - mu;
    float q = d0 * d0 + d1 * d1 + d2 * d2;
    for (int d = 32; d >= 1; d >>= 1) q += __shfl_xor(q, d, 64);
    float rstd = 1.f / sqrtf(q * (1.f / 192.f) + 1e-5f);
    ushort_t* yr = y + (size_t)row * CC;
    yr[lane]       = f2bf(d0 * rstd * g[lane]       + b[lane]);
    yr[lane + 64]  = f2bf(d1 * rstd * g[lane + 64]  + b[lane + 64]);
    yr[lane + 128] = f2bf(d2 * rstd * g[lane + 128] + b[lane + 128]);
}

// ---------------- points2img scatter + 2x downsample ----------------
__global__ void k_scatter(const float* __restrict__ pos, int* __restrict__ img)
{
    int t = blockIdx.x * 256 + threadIdx.x;
    int b = t / NPTS, n = t - b * NPTS;
    int x = (int)pos[(size_t)t * 2];
    int y = (int)pos[(size_t)t * 2 + 1];
    img[(size_t)b * NPTS + y * 112 + x] = n;
}

__global__ void k_down(const int* __restrict__ img, int* __restrict__ idxa)
{
    int q = blockIdx.x * 256 + threadIdx.x;
    int b = q / N2, p2 = q - b * N2;
    int r = p2 / 56, c = p2 - r * 56;
    idxa[q] = img[(size_t)b * NPTS + (2 * r) * 112 + 2 * c];
}

// ---------------- transpose lin_W -> fp8 linT[384][6144] ----------------
__global__ __launch_bounds__(256) void k_linT(const float* __restrict__ W, uchar* __restrict__ T)
{
    __shared__ float tile[64][65];
    int k0 = blockIdx.x * 64, n0 = blockIdx.y * 64;
    for (int s = 0; s < 16; ++s) {
        int id = threadIdx.x + s * 256;
        int i = id >> 6, j = id & 63;
        tile[i][j] = W[(size_t)(k0 + i) * 384 + n0 + j];
    }
    __syncthreads();
    for (int s = 0; s < 16; ++s) {
        int id = threadIdx.x + s * 256;
        int jj = id >> 6, ii = id & 63;
        T[(size_t)(n0 + jj) * 6144 + k0 + ii] = f2e4m3(tile[ii][jj]);
    }
}

// ---------------- precompute f1W MFMA B-fragments (bf16): frag[ks][w][lane][j] ----------------
__global__ __launch_bounds__(256) void k_prep(const float* __restrict__ f1W, ushort_t* __restrict__ frag)
{
    int t = blockIdx.x * 256 + threadIdx.x;   // 12288 total
    int j = t & 7;
    int lane = (t >> 3) & 63;
    int w = (t >> 9) & 3;
    int ks = t >> 11;
    int k = ks * 32 + (lane >> 4) * 8 + j;
    int o = w * 16 + (lane & 15);
    frag[t] = f2bf(f1W[k * 64 + o]);
}

// ---------------- per-point: sampling + weights + agg build (fp8) ----------------
__global__ __launch_bounds__(256) void k_point(
    const float* __restrict__ pos, const float* __restrict__ maskp,
    const int* __restrict__ massign, const int* __restrict__ memidx,
    const float* __restrict__ cmaskp, const ushort_t* __restrict__ featn,
    const int* __restrict__ idxarr, const ushort_t* __restrict__ f1frag,
    const float* __restrict__ w1W, const float* __restrict__ w1b,
    const float* __restrict__ lng, const float* __restrict__ lnb,
    const float* __restrict__ f1b,
    const float* __restrict__ f2W, const float* __restrict__ f2b,
    uchar* __restrict__ agg, float* __restrict__ outbuf, int p0)
{
    __shared__ double sc[128];
    __shared__ int memv[128];
    __shared__ double rs2[2];
    __shared__ int ri2[2];
    __shared__ int mcat[4];
    __shared__ float fg[4][200];
    __shared__ __align__(16) ushort_t frelb[4][200];
    __shared__ float prel[4][2];
    __shared__ float wsm[4][32];
    __shared__ float gpart[4][4];
    __shared__ float fwv[4];
    __shared__ float pd[2];

    int point = p0 + blockIdx.x;
    int b = point / N2;
    int tid = threadIdx.x;
    int wave = tid >> 6, lane = tid & 63;
    int l15 = lane & 15, l4 = lane >> 4;
    int idx_pt = idxarr[point];

    if (tid < 128) {
        int j = tid >> 4, i = tid & 15;
        int maj = massign[((size_t)b * NPTS + idx_pt) * 8 + j];
        size_t roff = ((size_t)b * KCL + maj) * 16 + i;
        int mv = memidx[roff];
        float cv = cmaskp[roff];
        if (mv == idx_pt) cv = 0.f;
        float pr = fmaxf(cv, 1e-5f);
        uint32 gi = (uint32)point * 128u + (uint32)tid;
        uint32 y0, y1;
        threefry(0u, gi, y0, y1);
        uint32 bits = y0 ^ y1;
        union { uint32 u; float f; } cu; cu.u = (bits >> 9) | 0x3f800000u;
        float u = cu.f - 1.0f;
        double gum = -log(-log((double)u + 1e-20) + 1e-20);
        sc[tid] = log((double)pr) + gum;
        memv[tid] = mv;
    }
    if (tid == 128) {
        pd[0] = pos[((size_t)b * NPTS + idx_pt) * 2];
        pd[1] = pos[((size_t)b * NPTS + idx_pt) * 2 + 1];
    }
    if (tid == 129) outbuf[OUT_MASK_OFF + point] = maskp[(size_t)b * NPTS + idx_pt];
    __syncthreads();
    if (tid < 2) outbuf[(size_t)point * 2 + tid] = floorf(pd[tid] * 0.5f);

    // top-3 (desc, ties -> lower index): wave-level argmax
    for (int pass = 0; pass < 3; ++pass) {
        double s = (tid < 128) ? sc[tid] : -1.0e300;
        int si = (tid < 128) ? tid : 0;
        for (int d = 32; d >= 1; d >>= 1) {
            double s2 = __shfl_xor(s, d, 64);
            int i2 = __shfl_xor(si, d, 64);
            if (s2 > s || (s2 == s && i2 < si)) { s = s2; si = i2; }
        }
        if (lane == 0 && wave < 2) { rs2[wave] = s; ri2[wave] = si; }
        __syncthreads();
        if (tid == 0) {
            int w = (rs2[1] > rs2[0] || (rs2[1] == rs2[0] && ri2[1] < ri2[0])) ? ri2[1] : ri2[0];
            mcat[pass] = memv[w];
            sc[w] = -1.0e300;
        }
        __syncthreads();
    }
    if (tid == 0) mcat[3] = idx_pt;
    __syncthreads();

    // gather 4 neighbor rows of feat_n (bf16 -> f32 LDS) + pos_rel
    {
        size_t rbase = ((size_t)b * NPTS + mcat[wave]) * CC;
        for (int jj = 0; jj < 3; ++jj) {
            int c = lane + jj * 64;
            fg[wave][c] = bf2f(featn[rbase + c]);
        }
        if (lane == 0) {
            prel[wave][0] = pos[((size_t)b * NPTS + mcat[wave]) * 2]     - pd[0];
            prel[wave][1] = pos[((size_t)b * NPTS + mcat[wave]) * 2 + 1] - pd[1];
        }
    }
    __syncthreads();

    // build feat_rel bf16 (rows 0..3), padded stride 200
    for (int it = 0; it < 3; ++it) {
        int idx = it * 256 + tid;          // < 768
        int mm = idx / 192, cq = idx - mm * 192;
        frelb[mm][cq] = f2bf(fg[mm][cq] - fg[3][cq]);
    }

    // pos MLP: (pos_rel @ w1) -> LN(32) -> gelu   (waves 0,1)
    if (tid < 128) {
        int mm = tid >> 5, kk = tid & 31;
        float pre = prel[mm][0] * w1W[kk] + prel[mm][1] * w1W[32 + kk] + w1b[kk];
        float s = pre;
        for (int d = 16; d >= 1; d >>= 1) s += __shfl_xor(s, d, 32);
        float mu = s * (1.f / 32.f);
        float dv = pre - mu;
        float vs = dv * dv;
        for (int d = 16; d >= 1; d >>= 1) vs += __shfl_xor(vs, d, 32);
        float var = vs * (1.f / 32.f);
        float nv = dv / sqrtf(var + 1e-5f) * lng[kk] + lnb[kk];
        wsm[mm][kk] = gelu_exact(nv);
    }
    __syncthreads();

    // feature gate via MFMA: h = feat_rel(4x192) @ f1W(192x64); wave w owns o-tile w*16
    {
        f32x4 acc = (f32x4){0.f, 0.f, 0.f, 0.f};
#pragma unroll
        for (int ks = 0; ks < 6; ++ks) {
            short8 av;
            if (l15 < 4) av = *(const short8*)(&frelb[l15][ks * 32 + l4 * 8]);
            else av = (short8){0,0,0,0,0,0,0,0};
            short8 bv = *(const short8*)(f1frag + ((size_t)(ks * 4 + wave) * 64 + lane) * 8);
            acc = __builtin_amdgcn_mfma_f32_16x16x32_bf16(av, bv, acc, 0, 0, 0);
        }
        float p0_ = 0.f, p1_ = 0.f, p2_ = 0.f, p3_ = 0.f;
        if (l4 == 0) {
            int o = wave * 16 + l15;
            float fb = f1b[o], fw2 = f2W[o];
            p0_ = gelu_exact(acc[0] + fb) * fw2;
            p1_ = gelu_exact(acc[1] + fb) * fw2;
            p2_ = gelu_exact(acc[2] + fb) * fw2;
            p3_ = gelu_exact(acc[3] + fb) * fw2;
        }
        for (int d = 8; d >= 1; d >>= 1) {
            p0_ += __shfl_xor(p0_, d, 64);
            p1_ += __shfl_xor(p1_, d, 64);
            p2_ += __shfl_xor(p2_, d, 64);
            p3_ += __shfl_xor(p3_, d, 64);
        }
        if (lane == 0) { gpart[wave][0] = p0_; gpart[wave][1] = p1_; gpart[wave][2] = p2_; gpart[wave][3] = p3_; }
    }
    __syncthreads();
    if (tid < 4) {
        float t = gpart[0][tid] + gpart[1][tid] + gpart[2][tid] + gpart[3][tid] + f2b[0];
        fwv[tid] = 1.f / (1.f + expf(-t));
    }
    __syncthreads();
    if (tid < 128) { int mm = tid >> 5, kk = tid & 31; wsm[mm][kk] *= fwv[mm]; }
    __syncthreads();

    // agg[k][c] = sum_m w[m][k] * feat_g[m][c]  -> fp8 e4m3 (pairs, never straddle a c-row)
    size_t abase = (size_t)point * 6144;
    for (int ii = 0; ii < 12; ++ii) {
        int kc = (ii * 256 + tid) * 2;
        int kq = kc / 192;
        int cq = kc - kq * 192;
        float v0 = wsm[0][kq] * fg[0][cq] + wsm[1][kq] * fg[1][cq]
                 + wsm[2][kq] * fg[2][cq] + wsm[3][kq] * fg[3][cq];
        float v1 = wsm[0][kq] * fg[0][cq + 1] + wsm[1][kq] * fg[1][cq + 1]
                 + wsm[2][kq] * fg[2][cq + 1] + wsm[3][kq] * fg[3][cq + 1];
        int pk = __builtin_amdgcn_cvt_pk_fp8_f32(v0, v1, 0, false);
        *(unsigned short*)(agg + abase + kc) = (unsigned short)(pk & 0xFFFF);
    }
}

// ---------------- GEMM: (cnt x 6144) @ (6144 x 384), fp8 MFMA, BK=64, dbuf prefetch ----------------
__global__ __launch_bounds__(256) void k_gemm(const uchar* __restrict__ A,
    const uchar* __restrict__ BT, const float* __restrict__ bias,
    float* __restrict__ out, int p0)
{
    // [buf][A=0/B=1][row 0..127][64]  = 32 KB
    __shared__ __align__(16) uchar lds[2][2][128][64];
    int tid = threadIdx.x;
    int wave = tid >> 6, lane = tid & 63;
    int l15 = lane & 15, l4 = lane >> 4;
    int m0 = blockIdx.x * 128;
    int n0 = blockIdx.y * 128;
    int wr = (wave >> 1) * 64, wc = (wave & 1) * 64;

    // staging geometry: row = wave*16 + (lane>>2) (+64 for 2nd half); slot = lane&3
    // LDS dest linear (base + lane*16); global source pre-swizzled: granule = slot ^ (row&3)
    int rr0 = wave * 16 + (lane >> 2);
    int sc0 = ((lane & 3) ^ ((lane >> 2) & 3)) * 16;
    const uchar* gaA0 = A  + (size_t)(p0 + m0 + rr0) * 6144 + sc0;
    const uchar* gaA1 = A  + (size_t)(p0 + m0 + rr0 + 64) * 6144 + sc0;
    const uchar* gaB0 = BT + (size_t)(n0 + rr0) * 6144 + sc0;
    const uchar* gaB1 = BT + (size_t)(n0 + rr0 + 64) * 6144 + sc0;

    f32x4 acc[4][4];
#pragma unroll
    for (int mi = 0; mi < 4; ++mi)
#pragma unroll
        for (int ni = 0; ni < 4; ++ni)
            acc[mi][ni] = (f32x4){0.f, 0.f, 0.f, 0.f};

    auto stage = [&](int buf, int k0) {
        gld16(gaA0 + k0, &lds[buf][0][wave * 16][0]);
        gld16(gaA1 + k0, &lds[buf][0][64 + wave * 16][0]);
        gld16(gaB0 + k0, &lds[buf][1][wave * 16][0]);
        gld16(gaB1 + k0, &lds[buf][1][64 + wave * 16][0]);
    };

    stage(0, 0);
    for (int t = 0; t < 96; ++t) {
        __syncthreads();                    // stage(t) landed; prior reads of buf done
        if (t + 1 < 96) stage((t + 1) & 1, (t + 1) * 64);
        const uchar* AsF = &lds[t & 1][0][0][0];
        const uchar* BsF = &lds[t & 1][1][0][0];
        long long av[4][2], bv[4][2];
#pragma unroll
        for (int mi = 0; mi < 4; ++mi) {
            int row = wr + mi * 16 + l15;
#pragma unroll
            for (int ks = 0; ks < 2; ++ks) {
                int slot = (ks * 2 + (l4 >> 1)) ^ (l15 & 3);
                av[mi][ks] = *(const long long*)(AsF + row * 64 + slot * 16 + (l4 & 1) * 8);
            }
        }
#pragma unroll
        for (int ni = 0; ni < 4; ++ni) {
            int row = wc + ni * 16 + l15;
#pragma unroll
            for (int ks = 0; ks < 2; ++ks) {
                int slot = (ks * 2 + (l4 >> 1)) ^ (l15 & 3);
                bv[ni][ks] = *(const long long*)(BsF + row * 64 + slot * 16 + (l4 & 1) * 8);
            }
        }
#pragma unroll
        for (int mi = 0; mi < 4; ++mi)
#pragma unroll
            for (int ni = 0; ni < 4; ++ni) {
                acc[mi][ni] = __builtin_amdgcn_mfma_f32_16x16x32_fp8_fp8(av[mi][0], bv[ni][0], acc[mi][ni], 0, 0, 0);
                acc[mi][ni] = __builtin_amdgcn_mfma_f32_16x16x32_fp8_fp8(av[mi][1], bv[ni][1], acc[mi][ni], 0, 0, 0);
            }
    }

#pragma unroll
    for (int mi = 0; mi < 4; ++mi)
#pragma unroll
        for (int ni = 0; ni < 4; ++ni)
#pragma unroll
            for (int r = 0; r < 4; ++r) {
                int rr = wr + mi * 16 + l4 * 4 + r;
                int ccol = wc + ni * 16 + l15;
                out[(size_t)(p0 + m0 + rr) * 384 + n0 + ccol] = acc[mi][ni][r] + bias[n0 + ccol];
            }
}

extern "C" void kernel_launch(void* const* d_in, const int* in_sizes, int n_in,
                              void* d_out, int out_size, void* d_ws, size_t ws_size,
                              hipStream_t stream)
{
    const float* pos      = (const float*)d_in[0];
    const float* feat     = (const float*)d_in[1];
    const float* maskp    = (const float*)d_in[2];
    const int*   massign  = (const int*)d_in[4];
    const int*   memidx   = (const int*)d_in[5];
    const float* cmaskp   = (const float*)d_in[9];
    const float* norm_g   = (const float*)d_in[10];
    const float* norm_b   = (const float*)d_in[11];
    const float* w1W      = (const float*)d_in[12];
    const float* w1b      = (const float*)d_in[13];
    const float* lng      = (const float*)d_in[14];
    const float* lnb      = (const float*)d_in[15];
    const float* f1W      = (const float*)d_in[16];
    const float* f1b      = (const float*)d_in[17];
    const float* f2W      = (const float*)d_in[18];
    const float* f2b      = (const float*)d_in[19];
    const float* linW     = (const float*)d_in[20];
    const float* linb     = (const float*)d_in[21];

    char* ws = (char*)d_ws;
    ushort_t* featn  = (ushort_t*)(ws);                 // 38,535,168 B
    int* img         = (int*)(ws + 38535168);           //    401,408 B
    int* idxa        = (int*)(ws + 38936576);           //    100,352 B
    uchar* linT      = (uchar*)(ws + 39036928);         //  2,359,296 B (fp8)
    ushort_t* f1frag = (ushort_t*)(ws + 41396224);      //     24,576 B
    uchar* agg       = (uchar*)(ws + 41420800);         // up to 154,140,672 B (fp8)

    size_t avail = ws_size > 41420800 ? ws_size - 41420800 : 0;
    long long slabM = (long long)(avail / 6144);
    slabM &= ~127LL;
    if (slabM > TOTPTS) slabM = TOTPTS;
    if (slabM < 128) slabM = 128;

    k_ln<<<TOTPTS, 256, 0, stream>>>(feat, norm_g, norm_b, featn);
    hipMemsetAsync(img, 0, 401408, stream);
    k_scatter<<<392, 256, 0, stream>>>(pos, img);
    k_down<<<98, 256, 0, stream>>>(img, idxa);
    k_linT<<<dim3(96, 6), 256, 0, stream>>>(linW, linT);
    k_prep<<<48, 256, 0, stream>>>(f1W, f1frag);

    float* outF = (float*)d_out;
    for (int p0 = 0; p0 < TOTPTS; p0 += (int)slabM) {
        int cnt = TOTPTS - p0; if (cnt > (int)slabM) cnt = (int)slabM;
        k_point<<<cnt, 256, 0, stream>>>(pos, maskp, massign, memidx, cmaskp, featn, idxa, f1frag,
                w1W, w1b, lng, lnb, f1b, f2W, f2b, agg, outF, p0);
        k_gemm<<<dim3(cnt / 128, 3), 256, 0, stream>>>(agg, linT, linb, outF + OUT_FEAT_OFF, p0);
    }
}

// Round 7
// 341.007 us; speedup vs baseline: 1.6864x; 1.0106x over previous
//
#include <hip/hip_runtime.h>

typedef unsigned short ushort_t;
typedef unsigned char uchar;
typedef unsigned int uint32;
typedef __attribute__((ext_vector_type(8))) short short8;
typedef __attribute__((ext_vector_type(4))) float f32x4;

#define BATCH 8
#define NPTS 12544
#define CC 192
#define KCL 784
#define N2 3136
#define TOTPTS 25088        // BATCH*N2
#define OUT_FEAT_OFF 50176
#define OUT_MASK_OFF 9683968
#define FNEG 3.402823466e38f

__device__ __forceinline__ ushort_t f2bf(float f) {
    union { float f; uint32 u; } v; v.f = f;
    uint32 u = v.u;
    uint32 r = (u + 0x7FFFu + ((u >> 16) & 1u)) >> 16;
    return (ushort_t)r;
}
__device__ __forceinline__ float bf2f(ushort_t h) {
    union { uint32 u; float f; } v; v.u = ((uint32)h) << 16;
    return v.f;
}
__device__ __forceinline__ float gelu_exact(float x) {
    return 0.5f * x * (1.f + erff(x * 0.70710678118654752f));
}
__device__ __forceinline__ uchar f2e4m3(float f) {
    return (uchar)(__builtin_amdgcn_cvt_pk_fp8_f32(f, f, 0, false) & 0xFF);
}

__device__ __forceinline__ void gld16(const void* g, void* l) {
    __builtin_amdgcn_global_load_lds((const __attribute__((address_space(1))) void*)g,
                                     (__attribute__((address_space(3))) void*)l, 16, 0, 0);
}

// JAX threefry2x32 with key = (0, 42)
__device__ __forceinline__ void threefry(uint32 x0, uint32 x1, uint32& y0, uint32& y1) {
    const uint32 k0 = 0u, k1 = 42u;
    const uint32 k2 = 0u ^ 42u ^ 0x1BD11BDAu;
#define ROT(v,r) (((v) << (r)) | ((v) >> (32 - (r))))
#define RND(r) { x0 += x1; x1 = ROT(x1, r); x1 ^= x0; }
    x0 += k0; x1 += k1;
    RND(13) RND(15) RND(26) RND(6)
    x0 += k1; x1 += k2 + 1u;
    RND(17) RND(29) RND(16) RND(24)
    x0 += k2; x1 += k0 + 2u;
    RND(13) RND(15) RND(26) RND(6)
    x0 += k0; x1 += k1 + 3u;
    RND(17) RND(29) RND(16) RND(24)
    x0 += k1; x1 += k2 + 4u;
    RND(13) RND(15) RND(26) RND(6)
    x0 += k2; x1 += k0 + 5u;
    y0 = x0; y1 = x1;
#undef RND
#undef ROT
}

// ---------------- LayerNorm of feat -> bf16 ----------------
__global__ __launch_bounds__(256) void k_ln(const float* __restrict__ x,
        const float* __restrict__ g, const float* __restrict__ b,
        ushort_t* __restrict__ y)
{
    int row = blockIdx.x * 4 + (threadIdx.x >> 6);
    int lane = threadIdx.x & 63;
    const float* xr = x + (size_t)row * CC;
    float v0 = xr[lane], v1 = xr[lane + 64], v2 = xr[lane + 128];
    float s = v0 + v1 + v2;
    for (int d = 32; d >= 1; d >>= 1) s += __shfl_xor(s, d, 64);
    float mu = s * (1.f / 192.f);
    float d0 = v0 - mu, d1 = v1 - mu, d2 = v2 - mu;
    float q = d0 * d0 + d1 * d1 + d2 * d2;
    for (int d = 32; d >= 1; d >>= 1) q += __shfl_xor(q, d, 64);
    float rstd = 1.f / sqrtf(q * (1.f / 192.f) + 1e-5f);
    ushort_t* yr = y + (size_t)row * CC;
    yr[lane]       = f2bf(d0 * rstd * g[lane]       + b[lane]);
    yr[lane + 64]  = f2bf(d1 * rstd * g[lane + 64]  + b[lane + 64]);
    yr[lane + 128] = f2bf(d2 * rstd * g[lane + 128] + b[lane + 128]);
}

// ---------------- points2img scatter + 2x downsample ----------------
__global__ void k_scatter(const float* __restrict__ pos, int* __restrict__ img)
{
    int t = blockIdx.x * 256 + threadIdx.x;
    int b = t / NPTS, n = t - b * NPTS;
    int x = (int)pos[(size_t)t * 2];
    int y = (int)pos[(size_t)t * 2 + 1];
    img[(size_t)b * NPTS + y * 112 + x] = n;
}

__global__ void k_down(const int* __restrict__ img, int* __restrict__ idxa)
{
    int q = blockIdx.x * 256 + threadIdx.x;
    int b = q / N2, p2 = q - b * N2;
    int r = p2 / 56, c = p2 - r * 56;
    idxa[q] = img[(size_t)b * NPTS + (2 * r) * 112 + 2 * c];
}

// ---------------- transpose lin_W -> fp8 linT[384][6144] ----------------
__global__ __launch_bounds__(256) void k_linT(const float* __restrict__ W, uchar* __restrict__ T)
{
    __shared__ float tile[64][65];
    int k0 = blockIdx.x * 64, n0 = blockIdx.y * 64;
    for (int s = 0; s < 16; ++s) {
        int id = threadIdx.x + s * 256;
        int i = id >> 6, j = id & 63;
        tile[i][j] = W[(size_t)(k0 + i) * 384 + n0 + j];
    }
    __syncthreads();
    for (int s = 0; s < 16; ++s) {
        int id = threadIdx.x + s * 256;
        int jj = id >> 6, ii = id & 63;
        T[(size_t)(n0 + jj) * 6144 + k0 + ii] = f2e4m3(tile[ii][jj]);
    }
}

// ---------------- precompute f1W MFMA B-fragments (bf16): frag[ks][w][lane][j] ----------------
__global__ __launch_bounds__(256) void k_prep(const float* __restrict__ f1W, ushort_t* __restrict__ frag)
{
    int t = blockIdx.x * 256 + threadIdx.x;   // 12288 total
    int j = t & 7;
    int lane = (t >> 3) & 63;
    int w = (t >> 9) & 3;
    int ks = t >> 11;
    int k = ks * 32 + (lane >> 4) * 8 + j;
    int o = w * 16 + (lane & 15);
    frag[t] = f2bf(f1W[k * 64 + o]);
}

// ---------------- per-point: sampling + weights + agg build (fp8) ----------------
__global__ __launch_bounds__(256) void k_point(
    const float* __restrict__ pos, const float* __restrict__ maskp,
    const int* __restrict__ massign, const int* __restrict__ memidx,
    const float* __restrict__ cmaskp, const ushort_t* __restrict__ featn,
    const int* __restrict__ idxarr, const ushort_t* __restrict__ f1frag,
    const float* __restrict__ w1W, const float* __restrict__ w1b,
    const float* __restrict__ lng, const float* __restrict__ lnb,
    const float* __restrict__ f1b,
    const float* __restrict__ f2W, const float* __restrict__ f2b,
    uchar* __restrict__ agg, float* __restrict__ outbuf, int p0)
{
    __shared__ float scf[128];
    __shared__ float prs[128];
    __shared__ float us[128];
    __shared__ double scd[128];
    __shared__ int memv[128];
    __shared__ float rsf[2];
    __shared__ int rif[2];
    __shared__ double rsd[2];
    __shared__ int rid[2];
    __shared__ float tops[4];
    __shared__ int topi[4];
    __shared__ int need64;
    __shared__ int mcat[4];
    __shared__ float fg[4][200];
    __shared__ __align__(16) ushort_t frelb[4][200];
    __shared__ float prel[4][2];
    __shared__ float wsm[4][32];
    __shared__ float gpart[4][4];
    __shared__ float fwv[4];
    __shared__ float pd[2];

    int point = p0 + blockIdx.x;
    int b = point / N2;
    int tid = threadIdx.x;
    int wave = tid >> 6, lane = tid & 63;
    int l15 = lane & 15, l4 = lane >> 4;
    int idx_pt = idxarr[point];

    if (tid < 128) {
        int j = tid >> 4, i = tid & 15;
        int maj = massign[((size_t)b * NPTS + idx_pt) * 8 + j];
        size_t roff = ((size_t)b * KCL + maj) * 16 + i;
        int mv = memidx[roff];
        float cv = cmaskp[roff];
        if (mv == idx_pt) cv = 0.f;
        float pr = fmaxf(cv, 1e-5f);
        uint32 gi = (uint32)point * 128u + (uint32)tid;
        uint32 y0, y1;
        threefry(0u, gi, y0, y1);
        uint32 bits = y0 ^ y1;
        union { uint32 u; float f; } cu; cu.u = (bits >> 9) | 0x3f800000u;
        float u = cu.f - 1.0f;
        // f32 fast-path score (HW log); exact f64 fallback below if boundary is tight
        float gum = -logf(-logf(u + 1e-20f) + 1e-20f);
        scf[tid] = logf(pr) + gum;
        prs[tid] = pr;
        us[tid] = u;
        memv[tid] = mv;
    }
    if (tid == 128) {
        pd[0] = pos[((size_t)b * NPTS + idx_pt) * 2];
        pd[1] = pos[((size_t)b * NPTS + idx_pt) * 2 + 1];
    }
    if (tid == 129) outbuf[OUT_MASK_OFF + point] = maskp[(size_t)b * NPTS + idx_pt];
    __syncthreads();
    if (tid < 2) outbuf[(size_t)point * 2 + tid] = floorf(pd[tid] * 0.5f);

    // top-4 f32 argmax (desc, ties -> lower index)
    for (int pass = 0; pass < 4; ++pass) {
        float s = (tid < 128) ? scf[tid] : -FNEG;
        int si = (tid < 128) ? tid : 0;
        for (int d = 32; d >= 1; d >>= 1) {
            float s2 = __shfl_xor(s, d, 64);
            int i2 = __shfl_xor(si, d, 64);
            if (s2 > s || (s2 == s && i2 < si)) { s = s2; si = i2; }
        }
        if (lane == 0 && wave < 2) { rsf[wave] = s; rif[wave] = si; }
        __syncthreads();
        if (tid == 0) {
            int w = (rsf[1] > rsf[0] || (rsf[1] == rsf[0] && rif[1] < rif[0])) ? rif[1] : rif[0];
            float ws = (rsf[1] > rsf[0] || (rsf[1] == rsf[0] && rif[1] < rif[0])) ? rsf[1] : rsf[0];
            tops[pass] = ws; topi[pass] = w;
            scf[w] = -FNEG;
        }
        __syncthreads();
    }
    if (tid == 0) {
        need64 = (tops[2] - tops[3] < 1e-4f);
        if (!need64) {
            mcat[0] = memv[topi[0]];
            mcat[1] = memv[topi[1]];
            mcat[2] = memv[topi[2]];
        }
        mcat[3] = idx_pt;
    }
    __syncthreads();

    if (need64) {
        // exact f64 re-scoring (rare path, matches numpy promotion semantics)
        if (tid < 128) {
            double gum = -log(-log((double)us[tid] + 1e-20) + 1e-20);
            scd[tid] = log((double)prs[tid]) + gum;
        }
        __syncthreads();
        for (int pass = 0; pass < 3; ++pass) {
            double s = (tid < 128) ? scd[tid] : -1.0e300;
            int si = (tid < 128) ? tid : 0;
            for (int d = 32; d >= 1; d >>= 1) {
                double s2 = __shfl_xor(s, d, 64);
                int i2 = __shfl_xor(si, d, 64);
                if (s2 > s || (s2 == s && i2 < si)) { s = s2; si = i2; }
            }
            if (lane == 0 && wave < 2) { rsd[wave] = s; rid[wave] = si; }
            __syncthreads();
            if (tid == 0) {
                int w = (rsd[1] > rsd[0] || (rsd[1] == rsd[0] && rid[1] < rid[0])) ? rid[1] : rid[0];
                mcat[pass] = memv[w];
                scd[w] = -1.0e300;
            }
            __syncthreads();
        }
    }

    // gather 4 neighbor rows of feat_n (bf16 -> f32 LDS) + pos_rel
    {
        size_t rbase = ((size_t)b * NPTS + mcat[wave]) * CC;
        for (int jj = 0; jj < 3; ++jj) {
            int c = lane + jj * 64;
            fg[wave][c] = bf2f(featn[rbase + c]);
        }
        if (lane == 0) {
            prel[wave][0] = pos[((size_t)b * NPTS + mcat[wave]) * 2]     - pd[0];
            prel[wave][1] = pos[((size_t)b * NPTS + mcat[wave]) * 2 + 1] - pd[1];
        }
    }
    __syncthreads();

    // build feat_rel bf16 (rows 0..3), padded stride 200
    for (int it = 0; it < 3; ++it) {
        int idx = it * 256 + tid;          // < 768
        int mm = idx / 192, cq = idx - mm * 192;
        frelb[mm][cq] = f2bf(fg[mm][cq] - fg[3][cq]);
    }

    // pos MLP: (pos_rel @ w1) -> LN(32) -> gelu   (waves 0,1)
    if (tid < 128) {
        int mm = tid >> 5, kk = tid & 31;
        float pre = prel[mm][0] * w1W[kk] + prel[mm][1] * w1W[32 + kk] + w1b[kk];
        float s = pre;
        for (int d = 16; d >= 1; d >>= 1) s += __shfl_xor(s, d, 32);
        float mu = s * (1.f / 32.f);
        float dv = pre - mu;
        float vs = dv * dv;
        for (int d = 16; d >= 1; d >>= 1) vs += __shfl_xor(vs, d, 32);
        float var = vs * (1.f / 32.f);
        float nv = dv / sqrtf(var + 1e-5f) * lng[kk] + lnb[kk];
        wsm[mm][kk] = gelu_exact(nv);
    }
    __syncthreads();

    // feature gate via MFMA: h = feat_rel(4x192) @ f1W(192x64); wave w owns o-tile w*16
    {
        f32x4 acc = (f32x4){0.f, 0.f, 0.f, 0.f};
#pragma unroll
        for (int ks = 0; ks < 6; ++ks) {
            short8 av;
            if (l15 < 4) av = *(const short8*)(&frelb[l15][ks * 32 + l4 * 8]);
            else av = (short8){0,0,0,0,0,0,0,0};
            short8 bv = *(const short8*)(f1frag + ((size_t)(ks * 4 + wave) * 64 + lane) * 8);
            acc = __builtin_amdgcn_mfma_f32_16x16x32_bf16(av, bv, acc, 0, 0, 0);
        }
        float p0_ = 0.f, p1_ = 0.f, p2_ = 0.f, p3_ = 0.f;
        if (l4 == 0) {
            int o = wave * 16 + l15;
            float fb = f1b[o], fw2 = f2W[o];
            p0_ = gelu_exact(acc[0] + fb) * fw2;
            p1_ = gelu_exact(acc[1] + fb) * fw2;
            p2_ = gelu_exact(acc[2] + fb) * fw2;
            p3_ = gelu_exact(acc[3] + fb) * fw2;
        }
        for (int d = 8; d >= 1; d >>= 1) {
            p0_ += __shfl_xor(p0_, d, 64);
            p1_ += __shfl_xor(p1_, d, 64);
            p2_ += __shfl_xor(p2_, d, 64);
            p3_ += __shfl_xor(p3_, d, 64);
        }
        if (lane == 0) { gpart[wave][0] = p0_; gpart[wave][1] = p1_; gpart[wave][2] = p2_; gpart[wave][3] = p3_; }
    }
    __syncthreads();
    if (tid < 4) {
        float t = gpart[0][tid] + gpart[1][tid] + gpart[2][tid] + gpart[3][tid] + f2b[0];
        fwv[tid] = 1.f / (1.f + expf(-t));
    }
    __syncthreads();
    if (tid < 128) { int mm = tid >> 5, kk = tid & 31; wsm[mm][kk] *= fwv[mm]; }
    __syncthreads();

    // agg[k][c] = sum_m w[m][k] * feat_g[m][c]  -> fp8 e4m3 (pairs, never straddle a c-row)
    size_t abase = (size_t)point * 6144;
    for (int ii = 0; ii < 12; ++ii) {
        int kc = (ii * 256 + tid) * 2;
        int kq = kc / 192;
        int cq = kc - kq * 192;
        float v0 = wsm[0][kq] * fg[0][cq] + wsm[1][kq] * fg[1][cq]
                 + wsm[2][kq] * fg[2][cq] + wsm[3][kq] * fg[3][cq];
        float v1 = wsm[0][kq] * fg[0][cq + 1] + wsm[1][kq] * fg[1][cq + 1]
                 + wsm[2][kq] * fg[2][cq + 1] + wsm[3][kq] * fg[3][cq + 1];
        int pk = __builtin_amdgcn_cvt_pk_fp8_f32(v0, v1, 0, false);
        *(unsigned short*)(agg + abase + kc) = (unsigned short)(pk & 0xFFFF);
    }
}

// ---------------- GEMM: (cnt x 6144) @ (6144 x 384), fp8 MFMA, BK=64, dbuf prefetch ----------------
__global__ __launch_bounds__(256) void k_gemm(const uchar* __restrict__ A,
    const uchar* __restrict__ BT, const float* __restrict__ bias,
    float* __restrict__ out, int p0)
{
    __shared__ __align__(16) uchar lds[2][2][128][64];
    int tid = threadIdx.x;
    int wave = tid >> 6, lane = tid & 63;
    int l15 = lane & 15, l4 = lane >> 4;
    int m0 = blockIdx.x * 128;
    int n0 = blockIdx.y * 128;
    int wr = (wave >> 1) * 64, wc = (wave & 1) * 64;

    int rr0 = wave * 16 + (lane >> 2);
    int sc0 = ((lane & 3) ^ ((lane >> 2) & 3)) * 16;
    const uchar* gaA0 = A  + (size_t)(p0 + m0 + rr0) * 6144 + sc0;
    const uchar* gaA1 = A  + (size_t)(p0 + m0 + rr0 + 64) * 6144 + sc0;
    const uchar* gaB0 = BT + (size_t)(n0 + rr0) * 6144 + sc0;
    const uchar* gaB1 = BT + (size_t)(n0 + rr0 + 64) * 6144 + sc0;

    f32x4 acc[4][4];
#pragma unroll
    for (int mi = 0; mi < 4; ++mi)
#pragma unroll
        for (int ni = 0; ni < 4; ++ni)
            acc[mi][ni] = (f32x4){0.f, 0.f, 0.f, 0.f};

    auto stage = [&](int buf, int k0) {
        gld16(gaA0 + k0, &lds[buf][0][wave * 16][0]);
        gld16(gaA1 + k0, &lds[buf][0][64 + wave * 16][0]);
        gld16(gaB0 + k0, &lds[buf][1][wave * 16][0]);
        gld16(gaB1 + k0, &lds[buf][1][64 + wave * 16][0]);
    };

    stage(0, 0);
    for (int t = 0; t < 96; ++t) {
        __syncthreads();
        if (t + 1 < 96) stage((t + 1) & 1, (t + 1) * 64);
        const uchar* AsF = &lds[t & 1][0][0][0];
        const uchar* BsF = &lds[t & 1][1][0][0];
        long long av[4][2], bv[4][2];
#pragma unroll
        for (int mi = 0; mi < 4; ++mi) {
            int row = wr + mi * 16 + l15;
#pragma unroll
            for (int ks = 0; ks < 2; ++ks) {
                int slot = (ks * 2 + (l4 >> 1)) ^ (l15 & 3);
                av[mi][ks] = *(const long long*)(AsF + row * 64 + slot * 16 + (l4 & 1) * 8);
            }
        }
#pragma unroll
        for (int ni = 0; ni < 4; ++ni) {
            int row = wc + ni * 16 + l15;
#pragma unroll
            for (int ks = 0; ks < 2; ++ks) {
                int slot = (ks * 2 + (l4 >> 1)) ^ (l15 & 3);
                bv[ni][ks] = *(const long long*)(BsF + row * 64 + slot * 16 + (l4 & 1) * 8);
            }
        }
#pragma unroll
        for (int mi = 0; mi < 4; ++mi)
#pragma unroll
            for (int ni = 0; ni < 4; ++ni) {
                acc[mi][ni] = __builtin_amdgcn_mfma_f32_16x16x32_fp8_fp8(av[mi][0], bv[ni][0], acc[mi][ni], 0, 0, 0);
                acc[mi][ni] = __builtin_amdgcn_mfma_f32_16x16x32_fp8_fp8(av[mi][1], bv[ni][1], acc[mi][ni], 0, 0, 0);
            }
    }

#pragma unroll
    for (int mi = 0; mi < 4; ++mi)
#pragma unroll
        for (int ni = 0; ni < 4; ++ni)
#pragma unroll
            for (int r = 0; r < 4; ++r) {
                int rr = wr + mi * 16 + l4 * 4 + r;
                int ccol = wc + ni * 16 + l15;
                out[(size_t)(p0 + m0 + rr) * 384 + n0 + ccol] = acc[mi][ni][r] + bias[n0 + ccol];
            }
}

extern "C" void kernel_launch(void* const* d_in, const int* in_sizes, int n_in,
                              void* d_out, int out_size, void* d_ws, size_t ws_size,
                              hipStream_t stream)
{
    const float* pos      = (const float*)d_in[0];
    const float* feat     = (const float*)d_in[1];
    const float* maskp    = (const float*)d_in[2];
    const int*   massign  = (const int*)d_in[4];
    const int*   memidx   = (const int*)d_in[5];
    const float* cmaskp   = (const float*)d_in[9];
    const float* norm_g   = (const float*)d_in[10];
    const float* norm_b   = (const float*)d_in[11];
    const float* w1W      = (const float*)d_in[12];
    const float* w1b      = (const float*)d_in[13];
    const float* lng      = (const float*)d_in[14];
    const float* lnb      = (const float*)d_in[15];
    const float* f1W      = (const float*)d_in[16];
    const float* f1b      = (const float*)d_in[17];
    const float* f2W      = (const float*)d_in[18];
    const float* f2b      = (const float*)d_in[19];
    const float* linW     = (const float*)d_in[20];
    const float* linb     = (const float*)d_in[21];

    char* ws = (char*)d_ws;
    ushort_t* featn  = (ushort_t*)(ws);                 // 38,535,168 B
    int* img         = (int*)(ws + 38535168);           //    401,408 B
    int* idxa        = (int*)(ws + 38936576);           //    100,352 B
    uchar* linT      = (uchar*)(ws + 39036928);         //  2,359,296 B (fp8)
    ushort_t* f1frag = (ushort_t*)(ws + 41396224);      //     24,576 B
    uchar* agg       = (uchar*)(ws + 41420800);         // up to 154,140,672 B (fp8)

    size_t avail = ws_size > 41420800 ? ws_size - 41420800 : 0;
    long long slabM = (long long)(avail / 6144);
    slabM &= ~127LL;
    if (slabM > TOTPTS) slabM = TOTPTS;
    if (slabM < 128) slabM = 128;

    k_ln<<<TOTPTS, 256, 0, stream>>>(feat, norm_g, norm_b, featn);
    hipMemsetAsync(img, 0, 401408, stream);
    k_scatter<<<392, 256, 0, stream>>>(pos, img);
    k_down<<<98, 256, 0, stream>>>(img, idxa);
    k_linT<<<dim3(96, 6), 256, 0, stream>>>(linW, linT);
    k_prep<<<48, 256, 0, stream>>>(f1W, f1frag);

    float* outF = (float*)d_out;
    for (int p0 = 0; p0 < TOTPTS; p0 += (int)slabM) {
        int cnt = TOTPTS - p0; if (cnt > (int)slabM) cnt = (int)slabM;
        k_point<<<cnt, 256, 0, stream>>>(pos, maskp, massign, memidx, cmaskp, featn, idxa, f1frag,
                w1W, w1b, lng, lnb, f1b, f2W, f2b, agg, outF, p0);
        k_gemm<<<dim3(cnt / 128, 3), 256, 0, stream>>>(agg, linT, linb, outF + OUT_FEAT_OFF, p0);
    }
}

// Round 8
// 319.955 us; speedup vs baseline: 1.7973x; 1.0658x over previous
//
#include <hip/hip_runtime.h>

typedef unsigned short ushort_t;
typedef unsigned char uchar;
typedef unsigned int uint32;
typedef __attribute__((ext_vector_type(8))) short short8;
typedef __attribute__((ext_vector_type(4))) float f32x4;
typedef __attribute__((ext_vector_type(2))) unsigned int u32x2;

#define BATCH 8
#define NPTS 12544
#define CC 192
#define KCL 784
#define N2 3136
#define TOTPTS 25088        // BATCH*N2
#define OUT_FEAT_OFF 50176
#define OUT_MASK_OFF 9683968
#define FNEG 3.402823466e38f

__device__ __forceinline__ ushort_t f2bf(float f) {
    union { float f; uint32 u; } v; v.f = f;
    uint32 u = v.u;
    uint32 r = (u + 0x7FFFu + ((u >> 16) & 1u)) >> 16;
    return (ushort_t)r;
}
__device__ __forceinline__ float bf2f(ushort_t h) {
    union { uint32 u; float f; } v; v.u = ((uint32)h) << 16;
    return v.f;
}
__device__ __forceinline__ float gelu_exact(float x) {
    return 0.5f * x * (1.f + erff(x * 0.70710678118654752f));
}
__device__ __forceinline__ uchar f2e4m3(float f) {
    return (uchar)(__builtin_amdgcn_cvt_pk_fp8_f32(f, f, 0, false) & 0xFF);
}

__device__ __forceinline__ void gld16(const void* g, void* l) {
    __builtin_amdgcn_global_load_lds((const __attribute__((address_space(1))) void*)g,
                                     (__attribute__((address_space(3))) void*)l, 16, 0, 0);
}

// JAX threefry2x32 with key = (0, 42)
__device__ __forceinline__ void threefry(uint32 x0, uint32 x1, uint32& y0, uint32& y1) {
    const uint32 k0 = 0u, k1 = 42u;
    const uint32 k2 = 0u ^ 42u ^ 0x1BD11BDAu;
#define ROT(v,r) (((v) << (r)) | ((v) >> (32 - (r))))
#define RND(r) { x0 += x1; x1 = ROT(x1, r); x1 ^= x0; }
    x0 += k0; x1 += k1;
    RND(13) RND(15) RND(26) RND(6)
    x0 += k1; x1 += k2 + 1u;
    RND(17) RND(29) RND(16) RND(24)
    x0 += k2; x1 += k0 + 2u;
    RND(13) RND(15) RND(26) RND(6)
    x0 += k0; x1 += k1 + 3u;
    RND(17) RND(29) RND(16) RND(24)
    x0 += k1; x1 += k2 + 4u;
    RND(13) RND(15) RND(26) RND(6)
    x0 += k2; x1 += k0 + 5u;
    y0 = x0; y1 = x1;
#undef RND
#undef ROT
}

// ---------------- LayerNorm of feat -> bf16 ----------------
__global__ __launch_bounds__(256) void k_ln(const float* __restrict__ x,
        const float* __restrict__ g, const float* __restrict__ b,
        ushort_t* __restrict__ y)
{
    int row = blockIdx.x * 4 + (threadIdx.x >> 6);
    int lane = threadIdx.x & 63;
    const float* xr = x + (size_t)row * CC;
    float v0 = xr[lane], v1 = xr[lane + 64], v2 = xr[lane + 128];
    float s = v0 + v1 + v2;
    for (int d = 32; d >= 1; d >>= 1) s += __shfl_xor(s, d, 64);
    float mu = s * (1.f / 192.f);
    float d0 = v0 - mu, d1 = v1 - mu, d2 = v2 - mu;
    float q = d0 * d0 + d1 * d1 + d2 * d2;
    for (int d = 32; d >= 1; d >>= 1) q += __shfl_xor(q, d, 64);
    float rstd = 1.f / sqrtf(q * (1.f / 192.f) + 1e-5f);
    ushort_t* yr = y + (size_t)row * CC;
    yr[lane]       = f2bf(d0 * rstd * g[lane]       + b[lane]);
    yr[lane + 64]  = f2bf(d1 * rstd * g[lane + 64]  + b[lane + 64]);
    yr[lane + 128] = f2bf(d2 * rstd * g[lane + 128] + b[lane + 128]);
}

// ---------------- points2img scatter + 2x downsample ----------------
__global__ void k_scatter(const float* __restrict__ pos, int* __restrict__ img)
{
    int t = blockIdx.x * 256 + threadIdx.x;
    int b = t / NPTS, n = t - b * NPTS;
    int x = (int)pos[(size_t)t * 2];
    int y = (int)pos[(size_t)t * 2 + 1];
    img[(size_t)b * NPTS + y * 112 + x] = n;
}

__global__ void k_down(const int* __restrict__ img, int* __restrict__ idxa)
{
    int q = blockIdx.x * 256 + threadIdx.x;
    int b = q / N2, p2 = q - b * N2;
    int r = p2 / 56, c = p2 - r * 56;
    idxa[q] = img[(size_t)b * NPTS + (2 * r) * 112 + 2 * c];
}

// ---------------- transpose lin_W -> fp8 linT[384][6144] ----------------
__global__ __launch_bounds__(256) void k_linT(const float* __restrict__ W, uchar* __restrict__ T)
{
    __shared__ float tile[64][65];
    int k0 = blockIdx.x * 64, n0 = blockIdx.y * 64;
    for (int s = 0; s < 16; ++s) {
        int id = threadIdx.x + s * 256;
        int i = id >> 6, j = id & 63;
        tile[i][j] = W[(size_t)(k0 + i) * 384 + n0 + j];
    }
    __syncthreads();
    for (int s = 0; s < 16; ++s) {
        int id = threadIdx.x + s * 256;
        int jj = id >> 6, ii = id & 63;
        T[(size_t)(n0 + jj) * 6144 + k0 + ii] = f2e4m3(tile[ii][jj]);
    }
}

// ---------------- precompute f1W MFMA B-fragments (bf16): frag[ks][w][lane][j] ----------------
__global__ __launch_bounds__(256) void k_prep(const float* __restrict__ f1W, ushort_t* __restrict__ frag)
{
    int t = blockIdx.x * 256 + threadIdx.x;   // 12288 total
    int j = t & 7;
    int lane = (t >> 3) & 63;
    int w = (t >> 9) & 3;
    int ks = t >> 11;
    int k = ks * 32 + (lane >> 4) * 8 + j;
    int o = w * 16 + (lane & 15);
    frag[t] = f2bf(f1W[k * 64 + o]);
}

// ---------------- per-point: sampling + weights + agg build (fp8) ----------------
__global__ __launch_bounds__(256) void k_point(
    const float* __restrict__ pos, const float* __restrict__ maskp,
    const int* __restrict__ massign, const int* __restrict__ memidx,
    const float* __restrict__ cmaskp, const ushort_t* __restrict__ featn,
    const int* __restrict__ idxarr, const ushort_t* __restrict__ f1frag,
    const float* __restrict__ w1W, const float* __restrict__ w1b,
    const float* __restrict__ lng, const float* __restrict__ lnb,
    const float* __restrict__ f1b,
    const float* __restrict__ f2W, const float* __restrict__ f2b,
    uchar* __restrict__ agg, float* __restrict__ outbuf, int p0)
{
    __shared__ float scf[128];
    __shared__ float prs[128];
    __shared__ float us[128];
    __shared__ int memv[128];
    __shared__ float fg[4][200];                      // row-major
    __shared__ __align__(16) float fgT[192][4];       // c-major, XOR-swizzled row index
    __shared__ __align__(16) ushort_t frelb[4][200];
    __shared__ float prel[4][2];
    __shared__ float wsm[4][32];
    __shared__ float gpart[4][4];
    __shared__ float fwv[4];

    int point = p0 + blockIdx.x;
    int b = point / N2;
    int tid = threadIdx.x;
    int wave = tid >> 6, lane = tid & 63;
    int l15 = lane & 15, l4 = lane >> 4;
    int idx_pt = idxarr[point];
    size_t browbase = (size_t)b * NPTS;

    // phase 1: scoring (128 threads)
    if (tid < 128) {
        int j = tid >> 4, i = tid & 15;
        int maj = massign[(browbase + idx_pt) * 8 + j];
        size_t roff = ((size_t)b * KCL + maj) * 16 + i;
        int mv = memidx[roff];
        float cv = cmaskp[roff];
        if (mv == idx_pt) cv = 0.f;
        float pr = fmaxf(cv, 1e-5f);
        uint32 gi = (uint32)point * 128u + (uint32)tid;
        uint32 y0, y1;
        threefry(0u, gi, y0, y1);
        uint32 bits = y0 ^ y1;
        union { uint32 u; float f; } cu; cu.u = (bits >> 9) | 0x3f800000u;
        float u = cu.f - 1.0f;
        float gum = -logf(-logf(u + 1e-20f) + 1e-20f);
        scf[tid] = logf(pr) + gum;
        prs[tid] = pr;
        us[tid] = u;
        memv[tid] = mv;
    }
    __syncthreads();   // #1: scores/memv ready

    float pdx = pos[(browbase + idx_pt) * 2];
    float pdy = pos[(browbase + idx_pt) * 2 + 1];
    if (wave == 3 && lane == 0) {
        outbuf[OUT_MASK_OFF + point] = maskp[browbase + idx_pt];
        outbuf[(size_t)point * 2]     = floorf(pdx * 0.5f);
        outbuf[(size_t)point * 2 + 1] = floorf(pdy * 0.5f);
    }

    // phase 2: per-wave redundant top-4 (barrierless, in-register knockout)
    float a0 = scf[lane], a1 = scf[lane + 64];
    float tops[4]; int topi[4];
#pragma unroll
    for (int pass = 0; pass < 4; ++pass) {
        float s; int si;
        if (a0 >= a1) { s = a0; si = lane; } else { s = a1; si = lane + 64; }
#pragma unroll
        for (int d = 32; d >= 1; d >>= 1) {
            float s2 = __shfl_xor(s, d, 64);
            int i2 = __shfl_xor(si, d, 64);
            if (s2 > s || (s2 == s && i2 < si)) { s = s2; si = i2; }
        }
        tops[pass] = s; topi[pass] = si;
        if (si == lane) a0 = -FNEG;
        if (si == lane + 64) a1 = -FNEG;
    }
    int mc0 = memv[topi[0]], mc1 = memv[topi[1]], mc2 = memv[topi[2]];
    if (tops[2] - tops[3] < 1e-4f) {
        // exact f64 fallback (rare): per-wave, in-register
        double b0 = log((double)prs[lane]) - log(-log((double)us[lane] + 1e-20) + 1e-20);
        double b1 = log((double)prs[lane + 64]) - log(-log((double)us[lane + 64] + 1e-20) + 1e-20);
        int mcs[3];
#pragma unroll
        for (int pass = 0; pass < 3; ++pass) {
            double s; int si;
            if (b0 >= b1) { s = b0; si = lane; } else { s = b1; si = lane + 64; }
            for (int d = 32; d >= 1; d >>= 1) {
                double s2 = __shfl_xor(s, d, 64);
                int i2 = __shfl_xor(si, d, 64);
                if (s2 > s || (s2 == s && i2 < si)) { s = s2; si = i2; }
            }
            mcs[pass] = memv[si];
            if (si == lane) b0 = -1.0e300;
            if (si == lane + 64) b1 = -1.0e300;
        }
        mc0 = mcs[0]; mc1 = mcs[1]; mc2 = mcs[2];
    }
    int myrow = idx_pt;
    if (wave == 0) myrow = mc0;
    else if (wave == 1) myrow = mc1;
    else if (wave == 2) myrow = mc2;

    // phase 3: gather (wave m -> row myrow): fg row-major + fgT swizzled c-major
    {
        size_t rbase = (browbase + myrow) * (size_t)CC;
#pragma unroll
        for (int jj = 0; jj < 3; ++jj) {
            int c = lane + jj * 64;
            float fv = bf2f(featn[rbase + c]);
            fg[wave][c] = fv;
            fgT[c ^ ((c >> 3) & 7)][wave] = fv;
        }
        if (lane == 0) {
            prel[wave][0] = pos[(browbase + myrow) * 2]     - pdx;
            prel[wave][1] = pos[(browbase + myrow) * 2 + 1] - pdy;
        }
    }
    __syncthreads();   // #2: fg, fgT, prel ready

    // phase 4a: frelb build (768 elems / 256 threads)
#pragma unroll
    for (int it = 0; it < 3; ++it) {
        int idx = it * 256 + tid;
        int mm = idx / 192, cq = idx - mm * 192;
        frelb[mm][cq] = f2bf(fg[mm][cq] - fg[3][cq]);
    }
    // phase 4b: pos MLP (128 threads)
    if (tid < 128) {
        int mm = tid >> 5, kk = tid & 31;
        float pre = prel[mm][0] * w1W[kk] + prel[mm][1] * w1W[32 + kk] + w1b[kk];
        float s = pre;
        for (int d = 16; d >= 1; d >>= 1) s += __shfl_xor(s, d, 32);
        float mu = s * (1.f / 32.f);
        float dv = pre - mu;
        float vs = dv * dv;
        for (int d = 16; d >= 1; d >>= 1) vs += __shfl_xor(vs, d, 32);
        float var = vs * (1.f / 32.f);
        float nv = dv / sqrtf(var + 1e-5f) * lng[kk] + lnb[kk];
        wsm[mm][kk] = gelu_exact(nv);
    }
    __syncthreads();   // #3: frelb, wsm ready

    // phase 5: gate MFMA; wave w owns o-tile w*16
    {
        f32x4 acc = (f32x4){0.f, 0.f, 0.f, 0.f};
#pragma unroll
        for (int ks = 0; ks < 6; ++ks) {
            short8 av;
            if (l15 < 4) av = *(const short8*)(&frelb[l15][ks * 32 + l4 * 8]);
            else av = (short8){0,0,0,0,0,0,0,0};
            short8 bv = *(const short8*)(f1frag + ((size_t)(ks * 4 + wave) * 64 + lane) * 8);
            acc = __builtin_amdgcn_mfma_f32_16x16x32_bf16(av, bv, acc, 0, 0, 0);
        }
        float p0_ = 0.f, p1_ = 0.f, p2_ = 0.f, p3_ = 0.f;
        if (l4 == 0) {
            int o = wave * 16 + l15;
            float fb = f1b[o], fw2 = f2W[o];
            p0_ = gelu_exact(acc[0] + fb) * fw2;
            p1_ = gelu_exact(acc[1] + fb) * fw2;
            p2_ = gelu_exact(acc[2] + fb) * fw2;
            p3_ = gelu_exact(acc[3] + fb) * fw2;
        }
        for (int d = 8; d >= 1; d >>= 1) {
            p0_ += __shfl_xor(p0_, d, 64);
            p1_ += __shfl_xor(p1_, d, 64);
            p2_ += __shfl_xor(p2_, d, 64);
            p3_ += __shfl_xor(p3_, d, 64);
        }
        if (lane == 0) { gpart[wave][0] = p0_; gpart[wave][1] = p1_; gpart[wave][2] = p2_; gpart[wave][3] = p3_; }
    }
    __syncthreads();   // #4: gpart ready
    if (tid < 4) {
        float t = gpart[0][tid] + gpart[1][tid] + gpart[2][tid] + gpart[3][tid] + f2b[0];
        fwv[tid] = 1.f / (1.f + expf(-t));
    }
    __syncthreads();   // #5: fwv ready

    // phase 6: agg[k][c] = sum_m (wsm[m][k]*fwv[m]) * fg[m][c] -> fp8
    {
        int k = tid >> 3, j = tid & 7, c0 = j * 24;
        float w0 = wsm[0][k] * fwv[0];
        float w1 = wsm[1][k] * fwv[1];
        float w2 = wsm[2][k] * fwv[2];
        float w3 = wsm[3][k] * fwv[3];
        float v[24];
#pragma unroll
        for (int i = 0; i < 24; ++i) {
            int c = c0 + i;
            const f32x4 q = *(const f32x4*)(&fgT[c ^ ((c >> 3) & 7)][0]);
            v[i] = w0 * q[0] + w1 * q[1] + w2 * q[2] + w3 * q[3];
        }
        uint32 r[6];
#pragma unroll
        for (int d = 0; d < 6; ++d) {
            uint32 t0 = __builtin_amdgcn_cvt_pk_fp8_f32(v[4 * d], v[4 * d + 1], 0, false);
            r[d] = __builtin_amdgcn_cvt_pk_fp8_f32(v[4 * d + 2], v[4 * d + 3], t0, true);
        }
        uchar* dst = agg + (size_t)point * 6144 + k * 192 + c0;   // 8B aligned
        *(u32x2*)(dst)      = (u32x2){r[0], r[1]};
        *(u32x2*)(dst + 8)  = (u32x2){r[2], r[3]};
        *(u32x2*)(dst + 16) = (u32x2){r[4], r[5]};
    }
}

// ---------------- GEMM: (cnt x 6144) @ (6144 x 384), fp8 MFMA, BK=64, dbuf prefetch ----------------
__global__ __launch_bounds__(256) void k_gemm(const uchar* __restrict__ A,
    const uchar* __restrict__ BT, const float* __restrict__ bias,
    float* __restrict__ out, int p0)
{
    __shared__ __align__(16) uchar lds[2][2][128][64];
    int tid = threadIdx.x;
    int wave = tid >> 6, lane = tid & 63;
    int l15 = lane & 15, l4 = lane >> 4;
    int m0 = blockIdx.x * 128;
    int n0 = blockIdx.y * 128;
    int wr = (wave >> 1) * 64, wc = (wave & 1) * 64;

    int rr0 = wave * 16 + (lane >> 2);
    int sc0 = ((lane & 3) ^ ((lane >> 2) & 3)) * 16;
    const uchar* gaA0 = A  + (size_t)(p0 + m0 + rr0) * 6144 + sc0;
    const uchar* gaA1 = A  + (size_t)(p0 + m0 + rr0 + 64) * 6144 + sc0;
    const uchar* gaB0 = BT + (size_t)(n0 + rr0) * 6144 + sc0;
    const uchar* gaB1 = BT + (size_t)(n0 + rr0 + 64) * 6144 + sc0;

    f32x4 acc[4][4];
#pragma unroll
    for (int mi = 0; mi < 4; ++mi)
#pragma unroll
        for (int ni = 0; ni < 4; ++ni)
            acc[mi][ni] = (f32x4){0.f, 0.f, 0.f, 0.f};

    auto stage = [&](int buf, int k0) {
        gld16(gaA0 + k0, &lds[buf][0][wave * 16][0]);
        gld16(gaA1 + k0, &lds[buf][0][64 + wave * 16][0]);
        gld16(gaB0 + k0, &lds[buf][1][wave * 16][0]);
        gld16(gaB1 + k0, &lds[buf][1][64 + wave * 16][0]);
    };

    stage(0, 0);
    for (int t = 0; t < 96; ++t) {
        __syncthreads();
        if (t + 1 < 96) stage((t + 1) & 1, (t + 1) * 64);
        const uchar* AsF = &lds[t & 1][0][0][0];
        const uchar* BsF = &lds[t & 1][1][0][0];
        long long av[4][2], bv[4][2];
#pragma unroll
        for (int mi = 0; mi < 4; ++mi) {
            int row = wr + mi * 16 + l15;
#pragma unroll
            for (int ks = 0; ks < 2; ++ks) {
                int slot = (ks * 2 + (l4 >> 1)) ^ (l15 & 3);
                av[mi][ks] = *(const long long*)(AsF + row * 64 + slot * 16 + (l4 & 1) * 8);
            }
        }
#pragma unroll
        for (int ni = 0; ni < 4; ++ni) {
            int row = wc + ni * 16 + l15;
#pragma unroll
            for (int ks = 0; ks < 2; ++ks) {
                int slot = (ks * 2 + (l4 >> 1)) ^ (l15 & 3);
                bv[ni][ks] = *(const long long*)(BsF + row * 64 + slot * 16 + (l4 & 1) * 8);
            }
        }
#pragma unroll
        for (int mi = 0; mi < 4; ++mi)
#pragma unroll
            for (int ni = 0; ni < 4; ++ni) {
                acc[mi][ni] = __builtin_amdgcn_mfma_f32_16x16x32_fp8_fp8(av[mi][0], bv[ni][0], acc[mi][ni], 0, 0, 0);
                acc[mi][ni] = __builtin_amdgcn_mfma_f32_16x16x32_fp8_fp8(av[mi][1], bv[ni][1], acc[mi][ni], 0, 0, 0);
            }
    }

#pragma unroll
    for (int mi = 0; mi < 4; ++mi)
#pragma unroll
        for (int ni = 0; ni < 4; ++ni)
#pragma unroll
            for (int r = 0; r < 4; ++r) {
                int rr = wr + mi * 16 + l4 * 4 + r;
                int ccol = wc + ni * 16 + l15;
                out[(size_t)(p0 + m0 + rr) * 384 + n0 + ccol] = acc[mi][ni][r] + bias[n0 + ccol];
            }
}

extern "C" void kernel_launch(void* const* d_in, const int* in_sizes, int n_in,
                              void* d_out, int out_size, void* d_ws, size_t ws_size,
                              hipStream_t stream)
{
    const float* pos      = (const float*)d_in[0];
    const float* feat     = (const float*)d_in[1];
    const float* maskp    = (const float*)d_in[2];
    const int*   massign  = (const int*)d_in[4];
    const int*   memidx   = (const int*)d_in[5];
    const float* cmaskp   = (const float*)d_in[9];
    const float* norm_g   = (const float*)d_in[10];
    const float* norm_b   = (const float*)d_in[11];
    const float* w1W      = (const float*)d_in[12];
    const float* w1b      = (const float*)d_in[13];
    const float* lng      = (const float*)d_in[14];
    const float* lnb      = (const float*)d_in[15];
    const float* f1W      = (const float*)d_in[16];
    const float* f1b      = (const float*)d_in[17];
    const float* f2W      = (const float*)d_in[18];
    const float* f2b      = (const float*)d_in[19];
    const float* linW     = (const float*)d_in[20];
    const float* linb     = (const float*)d_in[21];

    char* ws = (char*)d_ws;
    ushort_t* featn  = (ushort_t*)(ws);                 // 38,535,168 B
    int* img         = (int*)(ws + 38535168);           //    401,408 B
    int* idxa        = (int*)(ws + 38936576);           //    100,352 B
    uchar* linT      = (uchar*)(ws + 39036928);         //  2,359,296 B (fp8)
    ushort_t* f1frag = (ushort_t*)(ws + 41396224);      //     24,576 B
    uchar* agg       = (uchar*)(ws + 41420800);         // up to 154,140,672 B (fp8)

    size_t avail = ws_size > 41420800 ? ws_size - 41420800 : 0;
    long long slabM = (long long)(avail / 6144);
    slabM &= ~127LL;
    if (slabM > TOTPTS) slabM = TOTPTS;
    if (slabM < 128) slabM = 128;

    k_ln<<<TOTPTS, 256, 0, stream>>>(feat, norm_g, norm_b, featn);
    hipMemsetAsync(img, 0, 401408, stream);
    k_scatter<<<392, 256, 0, stream>>>(pos, img);
    k_down<<<98, 256, 0, stream>>>(img, idxa);
    k_linT<<<dim3(96, 6), 256, 0, stream>>>(linW, linT);
    k_prep<<<48, 256, 0, stream>>>(f1W, f1frag);

    float* outF = (float*)d_out;
    for (int p0 = 0; p0 < TOTPTS; p0 += (int)slabM) {
        int cnt = TOTPTS - p0; if (cnt > (int)slabM) cnt = (int)slabM;
        k_point<<<cnt, 256, 0, stream>>>(pos, maskp, massign, memidx, cmaskp, featn, idxa, f1frag,
                w1W, w1b, lng, lnb, f1b, f2W, f2b, agg, outF, p0);
        k_gemm<<<dim3(cnt / 128, 3), 256, 0, stream>>>(agg, linT, linb, outF + OUT_FEAT_OFF, p0);
    }
}